// Round 6
// baseline (210.655 us; speedup 1.0000x reference)
//
#include <hip/hip_runtime.h>
#include <hip/hip_bf16.h>
#include <hip/hip_fp16.h>
#include <math.h>

// ---------------------------------------------------------------------------
// Diffusion renoise-loop + conditional MLP loss, MI355X (gfx950).
// RNG: threefry_partitionable (bit-exact, absmax 0.0 rounds 1-13, 15-17).
// Round 18: round 17 proved the shared-SIMD ceiling (occupancy +50%, spill 0,
// conflicts 0 -> dur UNCHANGED, VALUBusy+MfmaUtil = 97%). Only lever left:
// instruction count. Rowmax reduce 4 -> 3 ops/tile via hybrid max3:
//   t01=fmaxf(a0,a1); t23=fmaxf(a2,a3)   (compiler v_max -- MFMA reads stay
//   compiler-managed, hazards inserted); bv=asm v_max3_f32(bv,t01,t23)
//   (inputs are VALU outputs only -- avoids round-14's MFMA->asm hazard).
// Exact max, order-independent -> decisions bit-identical.
#define BS   128
#define NS   1024
#define HID  512
#define CTX  128
#define TT   100
#define ITERS 8

// ---- workspace layout (bytes) ---------------------------------------------
constexpr size_t OFF_SACP  = 0;         // 100 f32
constexpr size_t OFF_S1M   = 512;       // 100 f32
constexpr size_t OFF_KEYS  = 1024;      // 16 u32
constexpr size_t OFF_CNTG  = 1152;      // u32[8][1024] -> 33920
constexpr size_t OFF_MASK  = 33920;     // u8[131072] -> 164992
constexpr size_t OFF_BIAS  = 262144;    // f32[128*512] -> 524288
constexpr size_t OFF_PA    = 524288;    // float4[512] -> 532480
constexpr size_t OFF_PB    = 532480;    // float4[512] -> 540672
constexpr size_t OFF_PC    = 540672;    // f32[512]   -> 542720
constexpr size_t OFF_PART  = 542720;    // f32[512]   -> 544768 (~0.55 MB)

typedef __attribute__((ext_vector_type(8))) _Float16 half8;
typedef __attribute__((ext_vector_type(4))) float f32x4;

// ---- threefry2x32-20 -------------------------------------------------------
__device__ __forceinline__ unsigned rotl32(unsigned x, int r) {
  return (x << r) | (x >> (32 - r));
}
__device__ __forceinline__ void tf2x32(unsigned k0, unsigned k1,
                                       unsigned x0, unsigned x1,
                                       unsigned& o0, unsigned& o1) {
  unsigned k2 = k0 ^ k1 ^ 0x1BD11BDAu;
  x0 += k0; x1 += k1;
#define TF_R4(a,b,c,d) \
  x0 += x1; x1 = rotl32(x1,(a)); x1 ^= x0; \
  x0 += x1; x1 = rotl32(x1,(b)); x1 ^= x0; \
  x0 += x1; x1 = rotl32(x1,(c)); x1 ^= x0; \
  x0 += x1; x1 = rotl32(x1,(d)); x1 ^= x0;
  TF_R4(13,15,26,6)   x0 += k1; x1 += k2 + 1u;
  TF_R4(17,29,16,24)  x0 += k2; x1 += k0 + 2u;
  TF_R4(13,15,26,6)   x0 += k0; x1 += k1 + 3u;
  TF_R4(17,29,16,24)  x0 += k1; x1 += k2 + 4u;
  TF_R4(13,15,26,6)   x0 += k2; x1 += k0 + 5u;
#undef TF_R4
  o0 = x0; o1 = x1;
}

__device__ __forceinline__ float bits_to_u(unsigned bits) {
  float f = __uint_as_float((bits >> 9) | 0x3f800000u) - 1.0f;
  float u = f * 2.0f + (-0.99999994f);
  return fmaxf(-0.99999994f, u);
}

__device__ __forceinline__ float nrm_from_idx(unsigned k0, unsigned k1, unsigned idx) {
  unsigned o0, o1;
  tf2x32(k0, k1, 0u, idx, o0, o1);
  return 1.41421356f * erfinvf(bits_to_u(o0 ^ o1));
}

__device__ __forceinline__ float ftanh(float x) {
  float e = __expf(2.0f * x);
  float r = __builtin_amdgcn_rcpf(e + 1.0f);
  return fmaf(-2.0f, r, 1.0f);
}

// 3-input max in one VALU slot. Inputs MUST be plain-VALU-produced values
// (never raw MFMA destinations -- round-14 failure mode). Exact maxNum for
// finite inputs, order-independent => decisions bit-identical to fmaxf chain.
__device__ __forceinline__ float max3f(float a, float b, float c) {
  float d;
  asm("v_max3_f32 %0, %1, %2, %3" : "=v"(d) : "v"(a), "v"(b), "v"(c));
  return d;
}

// fp16 hi/lo split: x ~= hi + lo with |err| <~ 2^-23 |x|
__device__ __forceinline__ void split16(float x, unsigned short& hi, unsigned short& lo) {
  __half h = __float2half(x);
  float hf = __half2float(h);
  __half l = __float2half(x - hf);
  hi = __half_as_ushort(h);
  lo = __half_as_ushort(l);
}
__device__ __forceinline__ unsigned pack2(unsigned short a, unsigned short b) {
  return (unsigned)a | ((unsigned)b << 16);
}
// duplicate low/high 16-bit half of u into both halves (1 v_perm_b32 each)
__device__ __forceinline__ unsigned dup_lo(unsigned u) {
  return __builtin_amdgcn_perm(u, u, 0x01000100u);  // bytes [0,1,0,1]
}
__device__ __forceinline__ unsigned dup_hi(unsigned u) {
  return __builtin_amdgcn_perm(u, u, 0x03020302u);  // bytes [2,3,2,3]
}

// ---- kernel 1: setup — blocks 0..255 bias, 256 weight pack, 257 tables -----
__global__ __launch_bounds__(256) void k_setup(
    const float* __restrict__ ctx, const float* __restrict__ Wc,
    const float* __restrict__ Wt, const float* __restrict__ b1,
    const int* __restrict__ ts, float* __restrict__ biasb,
    const float* __restrict__ W1, const float* __restrict__ W2,
    float4* __restrict__ PA, float4* __restrict__ PB, float* __restrict__ PC,
    float* __restrict__ sacp, float* __restrict__ s1m,
    unsigned* __restrict__ keys) {
  if (blockIdx.x == 257) {
    __shared__ double omb[TT];
    int t = threadIdx.x;
    if (t < TT) {
      const double PI = 3.14159265358979323846;
      double t0 = (double)t / TT, t1 = (double)(t + 1) / TT;
      double c0 = cos((t0 + 0.008) / 1.008 * PI * 0.5); double ab0 = c0 * c0;
      double c1 = cos((t1 + 0.008) / 1.008 * PI * 0.5); double ab1 = c1 * c1;
      double beta = 1.0 - ab1 / ab0;
      if (beta > 0.999) beta = 0.999;
      omb[t] = 1.0 - beta;
    }
    __syncthreads();
    if (t < TT) {
      double acp = 1.0;
      for (int i = 0; i <= t; ++i) acp *= omb[i];
      sacp[t] = (float)sqrt(acp);
      s1m[t]  = (float)sqrt(1.0 - acp);
    }
    if (t >= 128 && t < 128 + ITERS) {
      int k = t - 128;
      unsigned o0, o1;
      tf2x32(0u, 42u, 0u, (unsigned)k, o0, o1);
      keys[2*k] = o0; keys[2*k+1] = o1;
    }
    return;
  }
  if (blockIdx.x == 256) {
    for (int j = threadIdx.x; j < HID; j += 256) {
      PA[j] = make_float4(W1[j], W1[512 + j], W1[1024 + j], W1[1536 + j]);
      PB[j] = make_float4(W1[2048 + j], W1[2560 + j], W2[j*6 + 3], W2[j*6 + 4]);
      PC[j] = W2[j*6 + 5];
    }
    return;
  }
  __shared__ float sc[CTX];
  int b = blockIdx.x >> 1;
  int j = (blockIdx.x & 1) * 256 + (int)threadIdx.x;
  if (threadIdx.x < CTX) sc[threadIdx.x] = ctx[(size_t)b * CTX + threadIdx.x];
  __syncthreads();
  float acc = 0.f;
  for (int q = 0; q < CTX; ++q) acc = fmaf(sc[q], Wc[q * HID + j], acc);
  float temb = (float)ts[b] / 100.0f;
  biasb[b * HID + j] = acc + temb * Wt[j] + b1[j];
}

// ---- kernel 2: renoise — 1024 blocks (8 q-slices x 128 batches) ------------
// Block: 128 queries x 8 states; wave wv owns state p+2wv per parity p.
// Full 1024-record panel in LDS, 8 words/record, pair-swizzled:
//   word-pair p of row r lives at word offset r*8 + 2*(p ^ ((r>>2)&3)).
// Sequential g-passes keep register shape = round 15 (no spill).
__global__ __launch_bounds__(256, 4) void k_renoise(
    const float* __restrict__ data, const float* __restrict__ noise0,
    const int* __restrict__ ts, const float* __restrict__ sacp,
    const float* __restrict__ s1m, const unsigned* __restrict__ keys,
    unsigned* __restrict__ cntg, unsigned char* __restrict__ maskg) {
  __shared__ unsigned stw[8192];           // 32 KB: 1024 rec x 8 words
  __shared__ unsigned znyu4[4][128][3];    // 6 KB: pre-split noisy3-5
  __shared__ unsigned short mismb[8][8];   // 128 B
  __shared__ unsigned cnt[8];
  const int b = blockIdx.x & 127, qb = blockIdx.x >> 7;  // qb 0..7
  const int tid = (int)threadIdx.x;
  const int wv = tid >> 6, lane = tid & 63;
  const int c15 = lane & 15, quad = lane >> 4;
  const int n0 = qb * 128;
  const int t = ts[b];
  const float aa = sacp[t], ssv = s1m[t];
  if (tid < ITERS) cnt[tid] = 0u;
  // ---- stage full panel: 4 rows/thread, swizzled pair stores ---------------
#pragma unroll 1
  for (int ii = 0; ii < 4; ++ii) {
    int c = ii * 256 + tid;
    const float2* dp2 = (const float2*)(data + ((size_t)(b << 10) + c) * 6);
    float2 v0 = dp2[0], v1 = dp2[1], v2 = dp2[2];
    float dd[6] = {v0.x, v0.y, v1.x, v1.y, v2.x, v2.y};
    float dsq = dd[0]*dd[0];
    dsq = fmaf(dd[1], dd[1], dsq); dsq = fmaf(dd[2], dd[2], dsq);
    dsq = fmaf(dd[3], dd[3], dsq); dsq = fmaf(dd[4], dd[4], dsq);
    dsq = fmaf(dd[5], dd[5], dsq);
    unsigned U[6];
#pragma unroll
    for (int d = 0; d < 6; ++d) {
      unsigned short hi, lo; split16(dd[d], hi, lo);
      U[d] = pack2(hi, lo);
    }
    unsigned short vh, vl; split16(-0.5f * dsq, vh, vl);
    int sc_ = (c >> 2) & 3;
    unsigned* rec = stw + c * 8;
    *(uint2*)(rec + 2 * (0 ^ sc_)) = make_uint2(U[0], U[1]);
    *(uint2*)(rec + 2 * (1 ^ sc_)) = make_uint2(U[2], U[3]);
    *(uint2*)(rec + 2 * (2 ^ sc_)) = make_uint2(U[4], U[5]);
    *(uint2*)(rec + 2 * (3 ^ sc_)) = make_uint2(pack2(vh, vl), 0u);
  }
  // sweep A-gather base: lane (c15,quad) reads pair 'quad' of rows ct*16+c15;
  // (row>>2)&3 == c15>>2 for 16-aligned tile bases -> swizzle const per lane.
  const int abase = c15 * 8 + 2 * (quad ^ (c15 >> 2));
  // ---- two parities: p=0 -> states {0,2,4,6}, p=1 -> {1,3,5,7} -------------
#pragma unroll 1
  for (int p = 0; p < 2; ++p) {
    if (p == 1) __syncthreads();  // prior sweep done reading znyu4
    // fill znyu4: slot i holds state p+2i (verified round 16)
    {
      int lp = tid & 127;
      int pg = (b << 10) + n0 + lp;
      unsigned base6 = (unsigned)pg * 6u;
      const float* dp = data + (size_t)pg * 6;
      float d3 = dp[3], d4 = dp[4], d5 = dp[5];
#pragma unroll 1
      for (int k = 0; k < 2; ++k) {
        int slot = ((tid >> 7) << 1) + k;   // 0..3
        int s = p + 2 * slot;
        float z3, z4, z5;
        if (s == 0) {
          const float* np0 = noise0 + (size_t)pg * 6;
          z3 = np0[3]; z4 = np0[4]; z5 = np0[5];
        } else {
          unsigned kk0 = keys[2*(s-1)], kk1 = keys[2*(s-1)+1];
          z3 = nrm_from_idx(kk0, kk1, base6 + 3u);
          z4 = nrm_from_idx(kk0, kk1, base6 + 4u);
          z5 = nrm_from_idx(kk0, kk1, base6 + 5u);
        }
        float v3 = __fadd_rn(__fmul_rn(aa, d3), __fmul_rn(ssv, z3));
        float v4 = __fadd_rn(__fmul_rn(aa, d4), __fmul_rn(ssv, z4));
        float v5 = __fadd_rn(__fmul_rn(aa, d5), __fmul_rn(ssv, z5));
        unsigned short h_, l_;
        split16(v3, h_, l_); znyu4[slot][lp][0] = pack2(h_, l_);
        split16(v4, h_, l_); znyu4[slot][lp][1] = pack2(h_, l_);
        split16(v5, h_, l_); znyu4[slot][lp][2] = pack2(h_, l_);
      }
    }
    __syncthreads();  // stw (first parity) + znyu4 visible
    // ---- two sequential g-passes: 4 query tiles each -----------------------
#pragma unroll 1
    for (int g = 0; g < 2; ++g) {
      // build bq[4]: tile j covers queries (g*4+j)*16..+15, state p+2wv
      half8 bq[4];
#pragma unroll
      for (int j = 0; j < 4; ++j) {
        int lp = (g * 4 + j) * 16 + c15;
        int row = n0 + lp;
        int s_ = c15 >> 2;                  // == (row>>2)&3
        uint4 wds = make_uint4(0u, 0u, 0u, 0u);
        if (quad == 0) {
          uint2 u = *(const uint2*)(stw + row * 8 + 2 * (0 ^ s_));
          wds.x = dup_lo(u.x); wds.y = dup_hi(u.x);
          wds.z = dup_lo(u.y); wds.w = dup_hi(u.y);
        } else if (quad == 1) {
          unsigned ud = stw[row * 8 + 2 * (1 ^ s_)];   // word 2 (dim 2)
          unsigned uz = znyu4[wv][lp][0];
          wds.x = dup_lo(ud); wds.y = dup_hi(ud);
          wds.z = dup_lo(uz); wds.w = dup_hi(uz);
        } else if (quad == 2) {
          unsigned ua = znyu4[wv][lp][1];
          unsigned ub = znyu4[wv][lp][2];
          wds.x = dup_lo(ua); wds.y = dup_hi(ua);
          wds.z = dup_lo(ub); wds.w = dup_hi(ub);
        } else {
          wds.x = 0x3C003C00u;  // ones in the dsq slot; words 13..15 stay 0
        }
        bq[j] = __builtin_bit_cast(half8, wds);
      }
      // diag via gathered-A rows (bit-identical column dot products)
      float dvv[4];
#pragma unroll
      for (int j = 0; j < 4; ++j) {
        int row = n0 + (g * 4 + j) * 16 + c15;
        uint2 u = *(const uint2*)(stw + row * 8 + 2 * (quad ^ (c15 >> 2)));
        half8 ag = __builtin_bit_cast(half8, make_uint4(u.x, u.x, u.y, u.y));
        f32x4 z = {0.f, 0.f, 0.f, 0.f};
        f32x4 dacc = __builtin_amdgcn_mfma_f32_16x16x32_f16(ag, bq[j], z, 0, 0, 0);
        float d01 = (c15 & 1) ? dacc[1] : dacc[0];
        float d23 = (c15 & 1) ? dacc[3] : dacc[2];
        float dsend = (c15 & 2) ? d23 : d01;
        dvv[j] = __shfl(dsend, ((c15 >> 2) << 4) + c15);
      }
      // sweep all 64 candidate tiles, chunks of 4 with register dbuf prefetch
      float bv0 = -__builtin_inff(), bv1 = -__builtin_inff();
      float bv2 = -__builtin_inff(), bv3 = -__builtin_inff();
      uint2 cu[4], cun[4];
#pragma unroll
      for (int cc = 0; cc < 4; ++cc)
        cu[cc] = *(const uint2*)(stw + cc * 128 + abase);
#pragma unroll 1
      for (int ctc = 0; ctc < 16; ++ctc) {
        if (ctc < 15) {
#pragma unroll
          for (int cc = 0; cc < 4; ++cc)
            cun[cc] = *(const uint2*)(stw + ((ctc + 1) * 4 + cc) * 128 + abase);
        }
#pragma unroll
        for (int cc = 0; cc < 4; ++cc) {
          half8 ac = __builtin_bit_cast(half8,
                       make_uint4(cu[cc].x, cu[cc].x, cu[cc].y, cu[cc].y));
          f32x4 z = {0.f, 0.f, 0.f, 0.f};
          f32x4 a0 = __builtin_amdgcn_mfma_f32_16x16x32_f16(ac, bq[0], z, 0, 0, 0);
          f32x4 a1 = __builtin_amdgcn_mfma_f32_16x16x32_f16(ac, bq[1], z, 0, 0, 0);
          f32x4 a2 = __builtin_amdgcn_mfma_f32_16x16x32_f16(ac, bq[2], z, 0, 0, 0);
          f32x4 a3 = __builtin_amdgcn_mfma_f32_16x16x32_f16(ac, bq[3], z, 0, 0, 0);
          // hybrid reduce: MFMA results consumed ONLY by compiler v_max;
          // asm max3 sees only VALU-produced values (t01/t23/bv).
          {
            float t01 = fmaxf(a0[0], a0[1]);
            float t23 = fmaxf(a0[2], a0[3]);
            bv0 = max3f(bv0, t01, t23);
          }
          {
            float t01 = fmaxf(a1[0], a1[1]);
            float t23 = fmaxf(a1[2], a1[3]);
            bv1 = max3f(bv1, t01, t23);
          }
          {
            float t01 = fmaxf(a2[0], a2[1]);
            float t23 = fmaxf(a2[2], a2[3]);
            bv2 = max3f(bv2, t01, t23);
          }
          {
            float t01 = fmaxf(a3[0], a3[1]);
            float t23 = fmaxf(a3[2], a3[3]);
            bv3 = max3f(bv3, t01, t23);
          }
        }
        if (ctc < 15) {
#pragma unroll
          for (int cc = 0; cc < 4; ++cc) cu[cc] = cun[cc];
        }
      }
      // combine across quads (full rowmax per query col), ballot, record
      bv0 = fmaxf(bv0, __shfl_xor(bv0, 16)); bv0 = fmaxf(bv0, __shfl_xor(bv0, 32));
      bv1 = fmaxf(bv1, __shfl_xor(bv1, 16)); bv1 = fmaxf(bv1, __shfl_xor(bv1, 32));
      bv2 = fmaxf(bv2, __shfl_xor(bv2, 16)); bv2 = fmaxf(bv2, __shfl_xor(bv2, 32));
      bv3 = fmaxf(bv3, __shfl_xor(bv3, 16)); bv3 = fmaxf(bv3, __shfl_xor(bv3, 32));
      unsigned long long m0 = __ballot(bv0 > dvv[0]);
      unsigned long long m1 = __ballot(bv1 > dvv[1]);
      unsigned long long m2 = __ballot(bv2 > dvv[2]);
      unsigned long long m3 = __ballot(bv3 > dvv[3]);
      if (lane == 0) {
        int s = p + 2 * wv;
        mismb[s][g * 4 + 0] = (unsigned short)(m0 & 0xffffu);
        mismb[s][g * 4 + 1] = (unsigned short)(m1 & 0xffffu);
        mismb[s][g * 4 + 2] = (unsigned short)(m2 & 0xffffu);
        mismb[s][g * 4 + 3] = (unsigned short)(m3 & 0xffffu);
      }
    }
  }
  __syncthreads();
  // ---- per point: m_p = first matching state; mask; cnt_k ------------------
  if (tid < 128) {
    int mp = 8;
#pragma unroll
    for (int s = 0; s < 8; ++s) {
      if (mp == 8 && ((mismb[s][tid >> 4] >> (tid & 15)) & 1u) == 0u) mp = s;
    }
    maskg[(b << 10) + n0 + tid] = (unsigned char)((1u << mp) - 1u);
#pragma unroll
    for (int k = 0; k < ITERS; ++k) {
      unsigned long long mk = __ballot(mp > k ? 1 : 0);
      if (lane == 0) atomicAdd(&cnt[k], (unsigned)__popcll(mk));
    }
  }
  __syncthreads();
  if (tid < ITERS) cntg[tid * 1024 + (int)blockIdx.x] = cnt[tid];
}

// ---- kernel 3: MLP + masked SE, with fused finalize (exact cont gate) ------
__global__ __launch_bounds__(256) void k_loss(
    const float* __restrict__ data, const float* __restrict__ noise0,
    const int* __restrict__ ts, const float* __restrict__ sacp,
    const float* __restrict__ s1m, const unsigned* __restrict__ keys,
    const unsigned* __restrict__ cntg, const unsigned char* __restrict__ maskg,
    const float* __restrict__ biasb,
    const float4* __restrict__ PA, const float4* __restrict__ PB,
    const float* __restrict__ PC, const float* __restrict__ b2,
    float* __restrict__ part) {
  __shared__ float4 sA[HID];
  __shared__ float4 sB[HID];
  __shared__ float2 sCb[HID];
  __shared__ float zn[256][6];     // z3..z5, noisy3..5 per local point
  __shared__ float pp[4][3][256];  // per-wave partials
  __shared__ float red[4];
  __shared__ int ksh;
  int b = blockIdx.x >> 2, qq = blockIdx.x & 3;
  int tid = (int)threadIdx.x;
  int wv = tid >> 6, lane = tid & 63;
  // ---- phase 1: kstar from cntg --------------------------------------------
  if (tid < 64) {
    int ks = ITERS;
    for (int k2 = 0; k2 < ITERS; ++k2) {
      unsigned v = 0u;
#pragma unroll
      for (int i = 0; i < 16; ++i) v += cntg[k2 * 1024 + i * 64 + tid];
#pragma unroll
      for (int m = 32; m >= 1; m >>= 1) v += (unsigned)__shfl_xor((int)v, m);
      if (v < 10u && ks == ITERS) ks = k2;  // first failing iteration
    }
    if (tid == 0) ksh = ks;
  }
  // stage weights meanwhile
  for (int j = tid; j < HID; j += 256) {
    sA[j] = PA[j]; sB[j] = PB[j];
    sCb[j] = make_float2(PC[j], biasb[(size_t)b * HID + j]);
  }
  __syncthreads();
  // ---- phase 2: finalize this block's 256 points (1 per thread) ------------
  int p0 = (b << 10) + qq * 256;
  {
    int kstar = ksh;
    unsigned gate = (kstar >= ITERS) ? 0xFFu : ((1u << kstar) - 1u);
    int p = p0 + tid;
    int t = ts[b];
    float aa = sacp[t], ssv = s1m[t];
    unsigned m = (unsigned)maskg[p] & gate;
    float z3, z4, z5;
    if (m) {
      int j = 31 - __clz((int)m);  // last applied renoise iteration
      unsigned base6 = (unsigned)p * 6u;
      unsigned kk0 = keys[2*j], kk1 = keys[2*j+1];
      z3 = nrm_from_idx(kk0, kk1, base6 + 3u);
      z4 = nrm_from_idx(kk0, kk1, base6 + 4u);
      z5 = nrm_from_idx(kk0, kk1, base6 + 5u);
    } else {
      const float* np0 = noise0 + (size_t)p * 6;
      z3 = np0[3]; z4 = np0[4]; z5 = np0[5];
    }
    const float* dp = data + (size_t)p * 6;
    zn[tid][0] = z3; zn[tid][1] = z4; zn[tid][2] = z5;
    zn[tid][3] = __fadd_rn(__fmul_rn(aa, dp[3]), __fmul_rn(ssv, z3));
    zn[tid][4] = __fadd_rn(__fmul_rn(aa, dp[4]), __fmul_rn(ssv, z4));
    zn[tid][5] = __fadd_rn(__fmul_rn(aa, dp[5]), __fmul_rn(ssv, z5));
  }
  __syncthreads();
  // ---- phase 3: MLP, j-loop split across the 4 waves -----------------------
  float x[4][6];
  float a0[4], a1[4], a2[4];
#pragma unroll
  for (int q = 0; q < 4; ++q) {
    int pl = q * 64 + lane;
    int p = p0 + pl;
    x[q][0] = data[p*6+0]; x[q][1] = data[p*6+1]; x[q][2] = data[p*6+2];
    x[q][3] = zn[pl][3]; x[q][4] = zn[pl][4]; x[q][5] = zn[pl][5];
    a0[q] = 0.f; a1[q] = 0.f; a2[q] = 0.f;
  }
  int j0 = wv * 128;
#pragma unroll 2
  for (int jj = 0; jj < 128; ++jj) {
    int j = j0 + jj;
    float4 A = sA[j];
    float4 Bv = sB[j];
    float2 Cb = sCb[j];
#pragma unroll
    for (int q = 0; q < 4; ++q) {
      float s = x[q][0] * A.x;
      s = fmaf(x[q][1], A.y, s); s = fmaf(x[q][2], A.z, s);
      s = fmaf(x[q][3], A.w, s); s = fmaf(x[q][4], Bv.x, s);
      s = fmaf(x[q][5], Bv.y, s);
      s += Cb.y;
      float h = ftanh(s);
      a0[q] = fmaf(h, Bv.z, a0[q]);
      a1[q] = fmaf(h, Bv.w, a1[q]);
      a2[q] = fmaf(h, Cb.x, a2[q]);
    }
  }
#pragma unroll
  for (int q = 0; q < 4; ++q) {
    pp[wv][0][q * 64 + lane] = a0[q];
    pp[wv][1][q * 64 + lane] = a1[q];
    pp[wv][2][q * 64 + lane] = a2[q];
  }
  __syncthreads();
  float f0 = (pp[0][0][tid] + pp[1][0][tid] + pp[2][0][tid] + pp[3][0][tid])
             + b2[3] - zn[tid][0];
  float f1 = (pp[0][1][tid] + pp[1][1][tid] + pp[2][1][tid] + pp[3][1][tid])
             + b2[4] - zn[tid][1];
  float f2 = (pp[0][2][tid] + pp[1][2][tid] + pp[2][2][tid] + pp[3][2][tid])
             + b2[5] - zn[tid][2];
  float lsum = f0 * f0;
  lsum = fmaf(f1, f1, lsum);
  lsum = fmaf(f2, f2, lsum);
#pragma unroll
  for (int off = 32; off > 0; off >>= 1) lsum += __shfl_down(lsum, off);
  if ((tid & 63) == 0) red[tid >> 6] = lsum;
  __syncthreads();
  if (tid == 0) part[blockIdx.x] = red[0] + red[1] + red[2] + red[3];
}

// ---- kernel 4: final reduce ------------------------------------------------
__global__ void k_red(const float* __restrict__ part, float* __restrict__ out) {
  int b = (int)threadIdx.x;
  if (b < BS) {
    out[b] = (part[4*b] + part[4*b+1] + part[4*b+2] + part[4*b+3]) / 3072.0f;
  }
}

// ---------------------------------------------------------------------------
extern "C" void kernel_launch(void* const* d_in, const int* in_sizes, int n_in,
                              void* d_out, int out_size, void* d_ws, size_t ws_size,
                              hipStream_t stream) {
  (void)in_sizes; (void)n_in; (void)out_size; (void)ws_size;
  const float* data    = (const float*)d_in[0];
  const float* context = (const float*)d_in[1];
  const float* noise0  = (const float*)d_in[2];
  const float* W1      = (const float*)d_in[3];
  const float* Wc      = (const float*)d_in[4];
  const float* Wt      = (const float*)d_in[5];
  const float* b1      = (const float*)d_in[6];
  const float* W2      = (const float*)d_in[7];
  const float* b2      = (const float*)d_in[8];
  const int*   ts      = (const int*)d_in[9];
  float* out = (float*)d_out;

  char* w = (char*)d_ws;
  float*    sacp   = (float*)(w + OFF_SACP);
  float*    s1m    = (float*)(w + OFF_S1M);
  unsigned* keys   = (unsigned*)(w + OFF_KEYS);
  unsigned* cntg   = (unsigned*)(w + OFF_CNTG);
  unsigned char* maskg = (unsigned char*)(w + OFF_MASK);
  float*    biasb  = (float*)(w + OFF_BIAS);
  float4*   PA     = (float4*)(w + OFF_PA);
  float4*   PB     = (float4*)(w + OFF_PB);
  float*    PC     = (float*)(w + OFF_PC);
  float*    part   = (float*)(w + OFF_PART);

  k_setup<<<258, 256, 0, stream>>>(context, Wc, Wt, b1, ts, biasb,
                                   W1, W2, PA, PB, PC, sacp, s1m, keys);
  k_renoise<<<1024, 256, 0, stream>>>(data, noise0, ts, sacp, s1m, keys,
                                      cntg, maskg);
  k_loss<<<512, 256, 0, stream>>>(data, noise0, ts, sacp, s1m, keys, cntg,
                                  maskg, biasb, PA, PB, PC, b2, part);
  k_red<<<1, 128, 0, stream>>>(part, out);
}

// Round 7
// 188.724 us; speedup vs baseline: 1.1162x; 1.1162x over previous
//
#include <hip/hip_runtime.h>
#include <hip/hip_bf16.h>
#include <hip/hip_fp16.h>
#include <math.h>

// ---------------------------------------------------------------------------
// Diffusion renoise-loop + conditional MLP loss, MI355X (gfx950).
// RNG: threefry_partitionable (bit-exact, absmax 0.0 rounds 1-13, 15-17).
// Round 19: r18 proved inline asm poisons the hot loop (VALU time doubled);
// r17 proved VALU+MFMA share one SIMD resource (sum ~97%) and dense-state
// work is the floor. This round removes DEAD WORK: states are swept
// SEQUENTIALLY with tile-granular skip -- a point's states s > mp (first
// match) never affect the output (reference: matched points are frozen and
// re-test identically; state at iter k = min(mp,k); cnt_k = #{mp>k}).
// Expected: state 0 dense (1/8 of r17) + geometrically-collapsing remainder.
// Worst case = r17 + overhead. Inner sweep math verbatim r17 (verified).
#define BS   128
#define NS   1024
#define HID  512
#define CTX  128
#define TT   100
#define ITERS 8

// ---- workspace layout (bytes) ---------------------------------------------
constexpr size_t OFF_SACP  = 0;         // 100 f32
constexpr size_t OFF_S1M   = 512;       // 100 f32
constexpr size_t OFF_KEYS  = 1024;      // 16 u32
constexpr size_t OFF_CNTG  = 1152;      // u32[8][512] -> 17536
constexpr size_t OFF_MASK  = 33920;     // u8[131072] -> 164992
constexpr size_t OFF_BIAS  = 262144;    // f32[128*512] -> 524288
constexpr size_t OFF_PA    = 524288;    // float4[512] -> 532480
constexpr size_t OFF_PB    = 532480;    // float4[512] -> 540672
constexpr size_t OFF_PC    = 540672;    // f32[512]   -> 542720
constexpr size_t OFF_PART  = 542720;    // f32[512]   -> 544768 (~0.55 MB)

typedef __attribute__((ext_vector_type(8))) _Float16 half8;
typedef __attribute__((ext_vector_type(4))) float f32x4;

// ---- threefry2x32-20 -------------------------------------------------------
__device__ __forceinline__ unsigned rotl32(unsigned x, int r) {
  return (x << r) | (x >> (32 - r));
}
__device__ __forceinline__ void tf2x32(unsigned k0, unsigned k1,
                                       unsigned x0, unsigned x1,
                                       unsigned& o0, unsigned& o1) {
  unsigned k2 = k0 ^ k1 ^ 0x1BD11BDAu;
  x0 += k0; x1 += k1;
#define TF_R4(a,b,c,d) \
  x0 += x1; x1 = rotl32(x1,(a)); x1 ^= x0; \
  x0 += x1; x1 = rotl32(x1,(b)); x1 ^= x0; \
  x0 += x1; x1 = rotl32(x1,(c)); x1 ^= x0; \
  x0 += x1; x1 = rotl32(x1,(d)); x1 ^= x0;
  TF_R4(13,15,26,6)   x0 += k1; x1 += k2 + 1u;
  TF_R4(17,29,16,24)  x0 += k2; x1 += k0 + 2u;
  TF_R4(13,15,26,6)   x0 += k0; x1 += k1 + 3u;
  TF_R4(17,29,16,24)  x0 += k1; x1 += k2 + 4u;
  TF_R4(13,15,26,6)   x0 += k2; x1 += k0 + 5u;
#undef TF_R4
  o0 = x0; o1 = x1;
}

__device__ __forceinline__ float bits_to_u(unsigned bits) {
  float f = __uint_as_float((bits >> 9) | 0x3f800000u) - 1.0f;
  float u = f * 2.0f + (-0.99999994f);
  return fmaxf(-0.99999994f, u);
}

__device__ __forceinline__ float nrm_from_idx(unsigned k0, unsigned k1, unsigned idx) {
  unsigned o0, o1;
  tf2x32(k0, k1, 0u, idx, o0, o1);
  return 1.41421356f * erfinvf(bits_to_u(o0 ^ o1));
}

__device__ __forceinline__ float ftanh(float x) {
  float e = __expf(2.0f * x);
  float r = __builtin_amdgcn_rcpf(e + 1.0f);
  return fmaf(-2.0f, r, 1.0f);
}

// fp16 hi/lo split: x ~= hi + lo with |err| <~ 2^-23 |x|
__device__ __forceinline__ void split16(float x, unsigned short& hi, unsigned short& lo) {
  __half h = __float2half(x);
  float hf = __half2float(h);
  __half l = __float2half(x - hf);
  hi = __half_as_ushort(h);
  lo = __half_as_ushort(l);
}
__device__ __forceinline__ unsigned pack2(unsigned short a, unsigned short b) {
  return (unsigned)a | ((unsigned)b << 16);
}
// duplicate low/high 16-bit half of u into both halves (1 v_perm_b32 each)
__device__ __forceinline__ unsigned dup_lo(unsigned u) {
  return __builtin_amdgcn_perm(u, u, 0x01000100u);  // bytes [0,1,0,1]
}
__device__ __forceinline__ unsigned dup_hi(unsigned u) {
  return __builtin_amdgcn_perm(u, u, 0x03020302u);  // bytes [2,3,2,3]
}

// ---- kernel 1: setup — blocks 0..255 bias, 256 weight pack, 257 tables -----
__global__ __launch_bounds__(256) void k_setup(
    const float* __restrict__ ctx, const float* __restrict__ Wc,
    const float* __restrict__ Wt, const float* __restrict__ b1,
    const int* __restrict__ ts, float* __restrict__ biasb,
    const float* __restrict__ W1, const float* __restrict__ W2,
    float4* __restrict__ PA, float4* __restrict__ PB, float* __restrict__ PC,
    float* __restrict__ sacp, float* __restrict__ s1m,
    unsigned* __restrict__ keys) {
  if (blockIdx.x == 257) {
    __shared__ double omb[TT];
    int t = threadIdx.x;
    if (t < TT) {
      const double PI = 3.14159265358979323846;
      double t0 = (double)t / TT, t1 = (double)(t + 1) / TT;
      double c0 = cos((t0 + 0.008) / 1.008 * PI * 0.5); double ab0 = c0 * c0;
      double c1 = cos((t1 + 0.008) / 1.008 * PI * 0.5); double ab1 = c1 * c1;
      double beta = 1.0 - ab1 / ab0;
      if (beta > 0.999) beta = 0.999;
      omb[t] = 1.0 - beta;
    }
    __syncthreads();
    if (t < TT) {
      double acp = 1.0;
      for (int i = 0; i <= t; ++i) acp *= omb[i];
      sacp[t] = (float)sqrt(acp);
      s1m[t]  = (float)sqrt(1.0 - acp);
    }
    if (t >= 128 && t < 128 + ITERS) {
      int k = t - 128;
      unsigned o0, o1;
      tf2x32(0u, 42u, 0u, (unsigned)k, o0, o1);
      keys[2*k] = o0; keys[2*k+1] = o1;
    }
    return;
  }
  if (blockIdx.x == 256) {
    for (int j = threadIdx.x; j < HID; j += 256) {
      PA[j] = make_float4(W1[j], W1[512 + j], W1[1024 + j], W1[1536 + j]);
      PB[j] = make_float4(W1[2048 + j], W1[2560 + j], W2[j*6 + 3], W2[j*6 + 4]);
      PC[j] = W2[j*6 + 5];
    }
    return;
  }
  __shared__ float sc[CTX];
  int b = blockIdx.x >> 1;
  int j = (blockIdx.x & 1) * 256 + (int)threadIdx.x;
  if (threadIdx.x < CTX) sc[threadIdx.x] = ctx[(size_t)b * CTX + threadIdx.x];
  __syncthreads();
  float acc = 0.f;
  for (int q = 0; q < CTX; ++q) acc = fmaf(sc[q], Wc[q * HID + j], acc);
  float temb = (float)ts[b] / 100.0f;
  biasb[b * HID + j] = acc + temb * Wt[j] + b1[j];
}

// ---- kernel 2: renoise — 512 blocks (4 q-slices x 128 batches) -------------
// Sequential states with tile-granular skip. Block: 256 queries (16 tiles),
// full 1024-record swizzled panel in LDS (r17 layout). Per state: compute
// noisy for unmatched points, list active tiles (any unmatched point), waves
// sweep up to 4 active tiles each (inner loop verbatim r17), update mp.
// Early-exit when all points matched.
__global__ __launch_bounds__(256, 2) void k_renoise(
    const float* __restrict__ data, const float* __restrict__ noise0,
    const int* __restrict__ ts, const float* __restrict__ sacp,
    const float* __restrict__ s1m, const unsigned* __restrict__ keys,
    unsigned* __restrict__ cntg, unsigned char* __restrict__ maskg) {
  __shared__ unsigned stw[8192];           // 32 KB: 1024 rec x 8 words
  __shared__ unsigned znyu[256][3];        // 3 KB: pre-split noisy3-5
  __shared__ unsigned char mp[256];        // first matching state (8 = none)
  __shared__ unsigned short mismb[16];     // per-tile mism bits (this state)
  __shared__ unsigned long long wball[4];  // per-wave unmatched ballots
  __shared__ unsigned char act[16];        // active tile list
  __shared__ int nact_sh;
  __shared__ unsigned cnt[8];
  const int b = blockIdx.x & 127, qb = blockIdx.x >> 7;  // qb 0..3
  const int tid = (int)threadIdx.x;
  const int wv = tid >> 6, lane = tid & 63;
  const int c15 = lane & 15, quad = lane >> 4;
  const int n0 = qb * 256;
  const int t = ts[b];
  const float aa = sacp[t], ssv = s1m[t];
  if (tid < ITERS) cnt[tid] = 0u;
  mp[tid] = 8;
  // ---- stage full panel: 4 rows/thread, swizzled pair stores (r17) ---------
#pragma unroll 1
  for (int ii = 0; ii < 4; ++ii) {
    int c = ii * 256 + tid;
    const float2* dp2 = (const float2*)(data + ((size_t)(b << 10) + c) * 6);
    float2 v0 = dp2[0], v1 = dp2[1], v2 = dp2[2];
    float dd[6] = {v0.x, v0.y, v1.x, v1.y, v2.x, v2.y};
    float dsq = dd[0]*dd[0];
    dsq = fmaf(dd[1], dd[1], dsq); dsq = fmaf(dd[2], dd[2], dsq);
    dsq = fmaf(dd[3], dd[3], dsq); dsq = fmaf(dd[4], dd[4], dsq);
    dsq = fmaf(dd[5], dd[5], dsq);
    unsigned U[6];
#pragma unroll
    for (int d = 0; d < 6; ++d) {
      unsigned short hi, lo; split16(dd[d], hi, lo);
      U[d] = pack2(hi, lo);
    }
    unsigned short vh, vl; split16(-0.5f * dsq, vh, vl);
    int sc_ = (c >> 2) & 3;
    unsigned* rec = stw + c * 8;
    *(uint2*)(rec + 2 * (0 ^ sc_)) = make_uint2(U[0], U[1]);
    *(uint2*)(rec + 2 * (1 ^ sc_)) = make_uint2(U[2], U[3]);
    *(uint2*)(rec + 2 * (2 ^ sc_)) = make_uint2(U[4], U[5]);
    *(uint2*)(rec + 2 * (3 ^ sc_)) = make_uint2(pack2(vh, vl), 0u);
  }
  const int abase = c15 * 8 + 2 * (quad ^ (c15 >> 2));
  // ---- sequential states with tile skip ------------------------------------
#pragma unroll 1
  for (int s = 0; s < ITERS; ++s) {
    __syncthreads();  // prev mp updates + staging (s=0) visible
    // phase A: noisy for unmatched points; unmatched ballots
    bool unm = (mp[tid] == 8);
    if (unm) {
      int pg = (b << 10) + n0 + tid;
      unsigned base6 = (unsigned)pg * 6u;
      const float* dp = data + (size_t)pg * 6;
      float z3, z4, z5;
      if (s == 0) {
        const float* np0 = noise0 + (size_t)pg * 6;
        z3 = np0[3]; z4 = np0[4]; z5 = np0[5];
      } else {
        unsigned kk0 = keys[2*(s-1)], kk1 = keys[2*(s-1)+1];
        z3 = nrm_from_idx(kk0, kk1, base6 + 3u);
        z4 = nrm_from_idx(kk0, kk1, base6 + 4u);
        z5 = nrm_from_idx(kk0, kk1, base6 + 5u);
      }
      float v3 = __fadd_rn(__fmul_rn(aa, dp[3]), __fmul_rn(ssv, z3));
      float v4 = __fadd_rn(__fmul_rn(aa, dp[4]), __fmul_rn(ssv, z4));
      float v5 = __fadd_rn(__fmul_rn(aa, dp[5]), __fmul_rn(ssv, z5));
      unsigned short h_, l_;
      split16(v3, h_, l_); znyu[tid][0] = pack2(h_, l_);
      split16(v4, h_, l_); znyu[tid][1] = pack2(h_, l_);
      split16(v5, h_, l_); znyu[tid][2] = pack2(h_, l_);
    }
    unsigned long long bal = __ballot(unm ? 1 : 0);
    if (lane == 0) wball[wv] = bal;
    __syncthreads();
    if (tid == 0) {
      int n = 0;
#pragma unroll
      for (int tt_ = 0; tt_ < 16; ++tt_) {
        unsigned m16 = (unsigned)((wball[tt_ >> 2] >> ((tt_ & 3) << 4)) & 0xffffu);
        if (m16) act[n++] = (unsigned char)tt_;
      }
      nact_sh = n;
    }
    __syncthreads();
    int nact = nact_sh;
    if (nact == 0) break;  // all matched; later states identical
    // phase B: waves sweep their active tiles (up to 4, filled with t0)
    if (wv < nact) {
      int t0 = act[wv];
      int t1 = (wv + 4  < nact) ? act[wv + 4]  : t0;
      int t2 = (wv + 8  < nact) ? act[wv + 8]  : t0;
      int t3 = (wv + 12 < nact) ? act[wv + 12] : t0;
      int tt[4] = {t0, t1, t2, t3};
      // build bq[4]: tile tt[k], 16 query cols, state s (r17 layout)
      half8 bq[4];
#pragma unroll
      for (int k = 0; k < 4; ++k) {
        int lp = tt[k] * 16 + c15;
        int row = n0 + lp;
        int s_ = c15 >> 2;                  // == (row>>2)&3
        uint4 wds = make_uint4(0u, 0u, 0u, 0u);
        if (quad == 0) {
          uint2 u = *(const uint2*)(stw + row * 8 + 2 * (0 ^ s_));
          wds.x = dup_lo(u.x); wds.y = dup_hi(u.x);
          wds.z = dup_lo(u.y); wds.w = dup_hi(u.y);
        } else if (quad == 1) {
          unsigned ud = stw[row * 8 + 2 * (1 ^ s_)];
          unsigned uz = znyu[lp][0];
          wds.x = dup_lo(ud); wds.y = dup_hi(ud);
          wds.z = dup_lo(uz); wds.w = dup_hi(uz);
        } else if (quad == 2) {
          unsigned ua = znyu[lp][1];
          unsigned ub = znyu[lp][2];
          wds.x = dup_lo(ua); wds.y = dup_hi(ua);
          wds.z = dup_lo(ub); wds.w = dup_hi(ub);
        } else {
          wds.x = 0x3C003C00u;
        }
        bq[k] = __builtin_bit_cast(half8, wds);
      }
      // diag via gathered-A rows (r17)
      float dvv[4];
#pragma unroll
      for (int k = 0; k < 4; ++k) {
        int row = n0 + tt[k] * 16 + c15;
        uint2 u = *(const uint2*)(stw + row * 8 + 2 * (quad ^ (c15 >> 2)));
        half8 ag = __builtin_bit_cast(half8, make_uint4(u.x, u.x, u.y, u.y));
        f32x4 z = {0.f, 0.f, 0.f, 0.f};
        f32x4 dacc = __builtin_amdgcn_mfma_f32_16x16x32_f16(ag, bq[k], z, 0, 0, 0);
        float d01 = (c15 & 1) ? dacc[1] : dacc[0];
        float d23 = (c15 & 1) ? dacc[3] : dacc[2];
        float dsend = (c15 & 2) ? d23 : d01;
        dvv[k] = __shfl(dsend, ((c15 >> 2) << 4) + c15);
      }
      // sweep all 64 candidate tiles (r17 inner loop, verbatim)
      float bv0 = -__builtin_inff(), bv1 = -__builtin_inff();
      float bv2 = -__builtin_inff(), bv3 = -__builtin_inff();
      uint2 cu[4], cun[4];
#pragma unroll
      for (int cc = 0; cc < 4; ++cc)
        cu[cc] = *(const uint2*)(stw + cc * 128 + abase);
#pragma unroll 1
      for (int ctc = 0; ctc < 16; ++ctc) {
        if (ctc < 15) {
#pragma unroll
          for (int cc = 0; cc < 4; ++cc)
            cun[cc] = *(const uint2*)(stw + ((ctc + 1) * 4 + cc) * 128 + abase);
        }
#pragma unroll
        for (int cc = 0; cc < 4; ++cc) {
          half8 ac = __builtin_bit_cast(half8,
                       make_uint4(cu[cc].x, cu[cc].x, cu[cc].y, cu[cc].y));
          f32x4 z = {0.f, 0.f, 0.f, 0.f};
          f32x4 a0 = __builtin_amdgcn_mfma_f32_16x16x32_f16(ac, bq[0], z, 0, 0, 0);
          f32x4 a1 = __builtin_amdgcn_mfma_f32_16x16x32_f16(ac, bq[1], z, 0, 0, 0);
          f32x4 a2 = __builtin_amdgcn_mfma_f32_16x16x32_f16(ac, bq[2], z, 0, 0, 0);
          f32x4 a3 = __builtin_amdgcn_mfma_f32_16x16x32_f16(ac, bq[3], z, 0, 0, 0);
          bv0 = fmaxf(fmaxf(bv0, fmaxf(fmaxf(a0[0], a0[1]), a0[2])), a0[3]);
          bv1 = fmaxf(fmaxf(bv1, fmaxf(fmaxf(a1[0], a1[1]), a1[2])), a1[3]);
          bv2 = fmaxf(fmaxf(bv2, fmaxf(fmaxf(a2[0], a2[1]), a2[2])), a2[3]);
          bv3 = fmaxf(fmaxf(bv3, fmaxf(fmaxf(a3[0], a3[1]), a3[2])), a3[3]);
        }
        if (ctc < 15) {
#pragma unroll
          for (int cc = 0; cc < 4; ++cc) cu[cc] = cun[cc];
        }
      }
      bv0 = fmaxf(bv0, __shfl_xor(bv0, 16)); bv0 = fmaxf(bv0, __shfl_xor(bv0, 32));
      bv1 = fmaxf(bv1, __shfl_xor(bv1, 16)); bv1 = fmaxf(bv1, __shfl_xor(bv1, 32));
      bv2 = fmaxf(bv2, __shfl_xor(bv2, 16)); bv2 = fmaxf(bv2, __shfl_xor(bv2, 32));
      bv3 = fmaxf(bv3, __shfl_xor(bv3, 16)); bv3 = fmaxf(bv3, __shfl_xor(bv3, 32));
      unsigned long long m0 = __ballot(bv0 > dvv[0]);
      unsigned long long m1 = __ballot(bv1 > dvv[1]);
      unsigned long long m2 = __ballot(bv2 > dvv[2]);
      unsigned long long m3 = __ballot(bv3 > dvv[3]);
      if (lane == 0) {
        // filler duplicates write identical values (same tile, same inputs)
        mismb[t0] = (unsigned short)(m0 & 0xffffu);
        mismb[t1] = (unsigned short)(m1 & 0xffffu);
        mismb[t2] = (unsigned short)(m2 & 0xffffu);
        mismb[t3] = (unsigned short)(m3 & 0xffffu);
      }
    }
    __syncthreads();  // mismb visible
    // phase C: unmatched points that matched this state record mp = s
    if (mp[tid] == 8 &&
        (((unsigned)mismb[tid >> 4] >> (tid & 15)) & 1u) == 0u) {
      mp[tid] = (unsigned char)s;
    }
  }
  // ---- epilogue: maskg + cnt from mp (own-thread reads only) ---------------
  {
    int m = mp[tid];
    maskg[(b << 10) + n0 + tid] = (unsigned char)((1u << m) - 1u);
#pragma unroll
    for (int k = 0; k < ITERS; ++k) {
      unsigned long long mk = __ballot(m > k ? 1 : 0);
      if (lane == 0) atomicAdd(&cnt[k], (unsigned)__popcll(mk));
    }
  }
  __syncthreads();
  if (tid < ITERS) cntg[tid * 512 + (int)blockIdx.x] = cnt[tid];
}

// ---- kernel 3: MLP + masked SE, with fused finalize (exact cont gate) ------
__global__ __launch_bounds__(256) void k_loss(
    const float* __restrict__ data, const float* __restrict__ noise0,
    const int* __restrict__ ts, const float* __restrict__ sacp,
    const float* __restrict__ s1m, const unsigned* __restrict__ keys,
    const unsigned* __restrict__ cntg, const unsigned char* __restrict__ maskg,
    const float* __restrict__ biasb,
    const float4* __restrict__ PA, const float4* __restrict__ PB,
    const float* __restrict__ PC, const float* __restrict__ b2,
    float* __restrict__ part) {
  __shared__ float4 sA[HID];
  __shared__ float4 sB[HID];
  __shared__ float2 sCb[HID];
  __shared__ float zn[256][6];     // z3..z5, noisy3..5 per local point
  __shared__ float pp[4][3][256];  // per-wave partials
  __shared__ float red[4];
  __shared__ int ksh;
  int b = blockIdx.x >> 2, qq = blockIdx.x & 3;
  int tid = (int)threadIdx.x;
  int wv = tid >> 6, lane = tid & 63;
  // ---- phase 1: kstar from cntg --------------------------------------------
  if (tid < 64) {
    int ks = ITERS;
    for (int k2 = 0; k2 < ITERS; ++k2) {
      unsigned v = 0u;
#pragma unroll
      for (int i = 0; i < 8; ++i) v += cntg[k2 * 512 + i * 64 + tid];
#pragma unroll
      for (int m = 32; m >= 1; m >>= 1) v += (unsigned)__shfl_xor((int)v, m);
      if (v < 10u && ks == ITERS) ks = k2;  // first failing iteration
    }
    if (tid == 0) ksh = ks;
  }
  // stage weights meanwhile
  for (int j = tid; j < HID; j += 256) {
    sA[j] = PA[j]; sB[j] = PB[j];
    sCb[j] = make_float2(PC[j], biasb[(size_t)b * HID + j]);
  }
  __syncthreads();
  // ---- phase 2: finalize this block's 256 points (1 per thread) ------------
  int p0 = (b << 10) + qq * 256;
  {
    int kstar = ksh;
    unsigned gate = (kstar >= ITERS) ? 0xFFu : ((1u << kstar) - 1u);
    int p = p0 + tid;
    int t = ts[b];
    float aa = sacp[t], ssv = s1m[t];
    unsigned m = (unsigned)maskg[p] & gate;
    float z3, z4, z5;
    if (m) {
      int j = 31 - __clz((int)m);  // last applied renoise iteration
      unsigned base6 = (unsigned)p * 6u;
      unsigned kk0 = keys[2*j], kk1 = keys[2*j+1];
      z3 = nrm_from_idx(kk0, kk1, base6 + 3u);
      z4 = nrm_from_idx(kk0, kk1, base6 + 4u);
      z5 = nrm_from_idx(kk0, kk1, base6 + 5u);
    } else {
      const float* np0 = noise0 + (size_t)p * 6;
      z3 = np0[3]; z4 = np0[4]; z5 = np0[5];
    }
    const float* dp = data + (size_t)p * 6;
    zn[tid][0] = z3; zn[tid][1] = z4; zn[tid][2] = z5;
    zn[tid][3] = __fadd_rn(__fmul_rn(aa, dp[3]), __fmul_rn(ssv, z3));
    zn[tid][4] = __fadd_rn(__fmul_rn(aa, dp[4]), __fmul_rn(ssv, z4));
    zn[tid][5] = __fadd_rn(__fmul_rn(aa, dp[5]), __fmul_rn(ssv, z5));
  }
  __syncthreads();
  // ---- phase 3: MLP, j-loop split across the 4 waves -----------------------
  float x[4][6];
  float a0[4], a1[4], a2[4];
#pragma unroll
  for (int q = 0; q < 4; ++q) {
    int pl = q * 64 + lane;
    int p = p0 + pl;
    x[q][0] = data[p*6+0]; x[q][1] = data[p*6+1]; x[q][2] = data[p*6+2];
    x[q][3] = zn[pl][3]; x[q][4] = zn[pl][4]; x[q][5] = zn[pl][5];
    a0[q] = 0.f; a1[q] = 0.f; a2[q] = 0.f;
  }
  int j0 = wv * 128;
#pragma unroll 2
  for (int jj = 0; jj < 128; ++jj) {
    int j = j0 + jj;
    float4 A = sA[j];
    float4 Bv = sB[j];
    float2 Cb = sCb[j];
#pragma unroll
    for (int q = 0; q < 4; ++q) {
      float s = x[q][0] * A.x;
      s = fmaf(x[q][1], A.y, s); s = fmaf(x[q][2], A.z, s);
      s = fmaf(x[q][3], A.w, s); s = fmaf(x[q][4], Bv.x, s);
      s = fmaf(x[q][5], Bv.y, s);
      s += Cb.y;
      float h = ftanh(s);
      a0[q] = fmaf(h, Bv.z, a0[q]);
      a1[q] = fmaf(h, Bv.w, a1[q]);
      a2[q] = fmaf(h, Cb.x, a2[q]);
    }
  }
#pragma unroll
  for (int q = 0; q < 4; ++q) {
    pp[wv][0][q * 64 + lane] = a0[q];
    pp[wv][1][q * 64 + lane] = a1[q];
    pp[wv][2][q * 64 + lane] = a2[q];
  }
  __syncthreads();
  float f0 = (pp[0][0][tid] + pp[1][0][tid] + pp[2][0][tid] + pp[3][0][tid])
             + b2[3] - zn[tid][0];
  float f1 = (pp[0][1][tid] + pp[1][1][tid] + pp[2][1][tid] + pp[3][1][tid])
             + b2[4] - zn[tid][1];
  float f2 = (pp[0][2][tid] + pp[1][2][tid] + pp[2][2][tid] + pp[3][2][tid])
             + b2[5] - zn[tid][2];
  float lsum = f0 * f0;
  lsum = fmaf(f1, f1, lsum);
  lsum = fmaf(f2, f2, lsum);
#pragma unroll
  for (int off = 32; off > 0; off >>= 1) lsum += __shfl_down(lsum, off);
  if ((tid & 63) == 0) red[tid >> 6] = lsum;
  __syncthreads();
  if (tid == 0) part[blockIdx.x] = red[0] + red[1] + red[2] + red[3];
}

// ---- kernel 4: final reduce ------------------------------------------------
__global__ void k_red(const float* __restrict__ part, float* __restrict__ out) {
  int b = (int)threadIdx.x;
  if (b < BS) {
    out[b] = (part[4*b] + part[4*b+1] + part[4*b+2] + part[4*b+3]) / 3072.0f;
  }
}

// ---------------------------------------------------------------------------
extern "C" void kernel_launch(void* const* d_in, const int* in_sizes, int n_in,
                              void* d_out, int out_size, void* d_ws, size_t ws_size,
                              hipStream_t stream) {
  (void)in_sizes; (void)n_in; (void)out_size; (void)ws_size;
  const float* data    = (const float*)d_in[0];
  const float* context = (const float*)d_in[1];
  const float* noise0  = (const float*)d_in[2];
  const float* W1      = (const float*)d_in[3];
  const float* Wc      = (const float*)d_in[4];
  const float* Wt      = (const float*)d_in[5];
  const float* b1      = (const float*)d_in[6];
  const float* W2      = (const float*)d_in[7];
  const float* b2      = (const float*)d_in[8];
  const int*   ts      = (const int*)d_in[9];
  float* out = (float*)d_out;

  char* w = (char*)d_ws;
  float*    sacp   = (float*)(w + OFF_SACP);
  float*    s1m    = (float*)(w + OFF_S1M);
  unsigned* keys   = (unsigned*)(w + OFF_KEYS);
  unsigned* cntg   = (unsigned*)(w + OFF_CNTG);
  unsigned char* maskg = (unsigned char*)(w + OFF_MASK);
  float*    biasb  = (float*)(w + OFF_BIAS);
  float4*   PA     = (float4*)(w + OFF_PA);
  float4*   PB     = (float4*)(w + OFF_PB);
  float*    PC     = (float*)(w + OFF_PC);
  float*    part   = (float*)(w + OFF_PART);

  k_setup<<<258, 256, 0, stream>>>(context, Wc, Wt, b1, ts, biasb,
                                   W1, W2, PA, PB, PC, sacp, s1m, keys);
  k_renoise<<<512, 256, 0, stream>>>(data, noise0, ts, sacp, s1m, keys,
                                     cntg, maskg);
  k_loss<<<512, 256, 0, stream>>>(data, noise0, ts, sacp, s1m, keys, cntg,
                                  maskg, biasb, PA, PB, PC, b2, part);
  k_red<<<1, 128, 0, stream>>>(part, out);
}

// Round 8
// 181.436 us; speedup vs baseline: 1.1610x; 1.0402x over previous
//
#include <hip/hip_runtime.h>
#include <hip/hip_bf16.h>
#include <hip/hip_fp16.h>
#include <math.h>

// ---------------------------------------------------------------------------
// Diffusion renoise-loop + conditional MLP loss, MI355X (gfx950).
// RNG: threefry_partitionable (bit-exact, absmax 0.0 rounds 1-13, 15-17, 19).
// Round 20: r19's tile-granular skip failed to harvest the q~0.5 mismatch
// collapse (16-pt tiles stay active ~1-(1-q)^16~1; fillers re-dense the
// work; 24 barriers stall). This round: POINT-granular compaction, wave-
// autonomous. Per wave per state: ballot+mbcnt compacts unmatched points
// into znyS slots; nbq=ceil(nUnm/16) query tiles; sweep64<NBQ> scales with
// nbq; zero barriers in the state loop; wave breaks when all 64 matched.
// MFMA output col c depends only on B col c => gathered scores bit-identical.
#define BS   128
#define NS   1024
#define HID  512
#define CTX  128
#define TT   100
#define ITERS 8

// ---- workspace layout (bytes) ---------------------------------------------
constexpr size_t OFF_SACP  = 0;         // 100 f32
constexpr size_t OFF_S1M   = 512;       // 100 f32
constexpr size_t OFF_KEYS  = 1024;      // 16 u32
constexpr size_t OFF_CNTG  = 1152;      // u32[8][512] -> 17536
constexpr size_t OFF_MASK  = 33920;     // u8[131072] -> 164992
constexpr size_t OFF_BIAS  = 262144;    // f32[128*512] -> 524288
constexpr size_t OFF_PA    = 524288;    // float4[512] -> 532480
constexpr size_t OFF_PB    = 532480;    // float4[512] -> 540672
constexpr size_t OFF_PC    = 540672;    // f32[512]   -> 542720
constexpr size_t OFF_PART  = 542720;    // f32[512]   -> 544768 (~0.55 MB)

typedef __attribute__((ext_vector_type(8))) _Float16 half8;
typedef __attribute__((ext_vector_type(4))) float f32x4;

// ---- threefry2x32-20 -------------------------------------------------------
__device__ __forceinline__ unsigned rotl32(unsigned x, int r) {
  return (x << r) | (x >> (32 - r));
}
__device__ __forceinline__ void tf2x32(unsigned k0, unsigned k1,
                                       unsigned x0, unsigned x1,
                                       unsigned& o0, unsigned& o1) {
  unsigned k2 = k0 ^ k1 ^ 0x1BD11BDAu;
  x0 += k0; x1 += k1;
#define TF_R4(a,b,c,d) \
  x0 += x1; x1 = rotl32(x1,(a)); x1 ^= x0; \
  x0 += x1; x1 = rotl32(x1,(b)); x1 ^= x0; \
  x0 += x1; x1 = rotl32(x1,(c)); x1 ^= x0; \
  x0 += x1; x1 = rotl32(x1,(d)); x1 ^= x0;
  TF_R4(13,15,26,6)   x0 += k1; x1 += k2 + 1u;
  TF_R4(17,29,16,24)  x0 += k2; x1 += k0 + 2u;
  TF_R4(13,15,26,6)   x0 += k0; x1 += k1 + 3u;
  TF_R4(17,29,16,24)  x0 += k1; x1 += k2 + 4u;
  TF_R4(13,15,26,6)   x0 += k2; x1 += k0 + 5u;
#undef TF_R4
  o0 = x0; o1 = x1;
}

__device__ __forceinline__ float bits_to_u(unsigned bits) {
  float f = __uint_as_float((bits >> 9) | 0x3f800000u) - 1.0f;
  float u = f * 2.0f + (-0.99999994f);
  return fmaxf(-0.99999994f, u);
}

__device__ __forceinline__ float nrm_from_idx(unsigned k0, unsigned k1, unsigned idx) {
  unsigned o0, o1;
  tf2x32(k0, k1, 0u, idx, o0, o1);
  return 1.41421356f * erfinvf(bits_to_u(o0 ^ o1));
}

__device__ __forceinline__ float ftanh(float x) {
  float e = __expf(2.0f * x);
  float r = __builtin_amdgcn_rcpf(e + 1.0f);
  return fmaf(-2.0f, r, 1.0f);
}

// fp16 hi/lo split: x ~= hi + lo with |err| <~ 2^-23 |x|
__device__ __forceinline__ void split16(float x, unsigned short& hi, unsigned short& lo) {
  __half h = __float2half(x);
  float hf = __half2float(h);
  __half l = __float2half(x - hf);
  hi = __half_as_ushort(h);
  lo = __half_as_ushort(l);
}
__device__ __forceinline__ unsigned pack2(unsigned short a, unsigned short b) {
  return (unsigned)a | ((unsigned)b << 16);
}
// duplicate low/high 16-bit half of u into both halves (1 v_perm_b32 each)
__device__ __forceinline__ unsigned dup_lo(unsigned u) {
  return __builtin_amdgcn_perm(u, u, 0x01000100u);  // bytes [0,1,0,1]
}
__device__ __forceinline__ unsigned dup_hi(unsigned u) {
  return __builtin_amdgcn_perm(u, u, 0x03020302u);  // bytes [2,3,2,3]
}

// ---- variable-width candidate sweep: NBQ query tiles over 64 cand tiles ----
template<int NBQ>
__device__ __forceinline__ void sweep64(const unsigned* stw, int abase,
                                        const half8* bq, float* bv) {
#pragma unroll
  for (int k = 0; k < NBQ; ++k) bv[k] = -__builtin_inff();
  uint2 cu[4], cun[4];
#pragma unroll
  for (int cc = 0; cc < 4; ++cc)
    cu[cc] = *(const uint2*)(stw + cc * 128 + abase);
#pragma unroll 1
  for (int ctc = 0; ctc < 16; ++ctc) {
    if (ctc < 15) {
#pragma unroll
      for (int cc = 0; cc < 4; ++cc)
        cun[cc] = *(const uint2*)(stw + ((ctc + 1) * 4 + cc) * 128 + abase);
    }
#pragma unroll
    for (int cc = 0; cc < 4; ++cc) {
      half8 ac = __builtin_bit_cast(half8,
                   make_uint4(cu[cc].x, cu[cc].x, cu[cc].y, cu[cc].y));
      f32x4 z = {0.f, 0.f, 0.f, 0.f};
#pragma unroll
      for (int k = 0; k < NBQ; ++k) {
        f32x4 a = __builtin_amdgcn_mfma_f32_16x16x32_f16(ac, bq[k], z, 0, 0, 0);
        bv[k] = fmaxf(fmaxf(bv[k], fmaxf(fmaxf(a[0], a[1]), a[2])), a[3]);
      }
    }
    if (ctc < 15) {
#pragma unroll
      for (int cc = 0; cc < 4; ++cc) cu[cc] = cun[cc];
    }
  }
}

// ---- kernel 1: setup — blocks 0..255 bias, 256 weight pack, 257 tables -----
__global__ __launch_bounds__(256) void k_setup(
    const float* __restrict__ ctx, const float* __restrict__ Wc,
    const float* __restrict__ Wt, const float* __restrict__ b1,
    const int* __restrict__ ts, float* __restrict__ biasb,
    const float* __restrict__ W1, const float* __restrict__ W2,
    float4* __restrict__ PA, float4* __restrict__ PB, float* __restrict__ PC,
    float* __restrict__ sacp, float* __restrict__ s1m,
    unsigned* __restrict__ keys) {
  if (blockIdx.x == 257) {
    __shared__ double omb[TT];
    int t = threadIdx.x;
    if (t < TT) {
      const double PI = 3.14159265358979323846;
      double t0 = (double)t / TT, t1 = (double)(t + 1) / TT;
      double c0 = cos((t0 + 0.008) / 1.008 * PI * 0.5); double ab0 = c0 * c0;
      double c1 = cos((t1 + 0.008) / 1.008 * PI * 0.5); double ab1 = c1 * c1;
      double beta = 1.0 - ab1 / ab0;
      if (beta > 0.999) beta = 0.999;
      omb[t] = 1.0 - beta;
    }
    __syncthreads();
    if (t < TT) {
      double acp = 1.0;
      for (int i = 0; i <= t; ++i) acp *= omb[i];
      sacp[t] = (float)sqrt(acp);
      s1m[t]  = (float)sqrt(1.0 - acp);
    }
    if (t >= 128 && t < 128 + ITERS) {
      int k = t - 128;
      unsigned o0, o1;
      tf2x32(0u, 42u, 0u, (unsigned)k, o0, o1);
      keys[2*k] = o0; keys[2*k+1] = o1;
    }
    return;
  }
  if (blockIdx.x == 256) {
    for (int j = threadIdx.x; j < HID; j += 256) {
      PA[j] = make_float4(W1[j], W1[512 + j], W1[1024 + j], W1[1536 + j]);
      PB[j] = make_float4(W1[2048 + j], W1[2560 + j], W2[j*6 + 3], W2[j*6 + 4]);
      PC[j] = W2[j*6 + 5];
    }
    return;
  }
  __shared__ float sc[CTX];
  int b = blockIdx.x >> 1;
  int j = (blockIdx.x & 1) * 256 + (int)threadIdx.x;
  if (threadIdx.x < CTX) sc[threadIdx.x] = ctx[(size_t)b * CTX + threadIdx.x];
  __syncthreads();
  float acc = 0.f;
  for (int q = 0; q < CTX; ++q) acc = fmaf(sc[q], Wc[q * HID + j], acc);
  float temb = (float)ts[b] / 100.0f;
  biasb[b * HID + j] = acc + temb * Wt[j] + b1[j];
}

// ---- kernel 2: renoise — 512 blocks (4 q-slices x 128 batches) -------------
// Wave-autonomous sequential states with point compaction. Wave owns 64
// queries; per state: ballot+mbcnt -> compact unmatched into znyS[wv] slots
// (pre-split noisy words + row), nbq=ceil(nUnm/16) gathered query tiles,
// sweep64<nbq>, ballot-compare, mp update from wave-uniform masks. No
// barriers in the loop; wave exits when all its points matched.
__global__ __launch_bounds__(256, 2) void k_renoise(
    const float* __restrict__ data, const float* __restrict__ noise0,
    const int* __restrict__ ts, const float* __restrict__ sacp,
    const float* __restrict__ s1m, const unsigned* __restrict__ keys,
    unsigned* __restrict__ cntg, unsigned char* __restrict__ maskg) {
  __shared__ unsigned stw[8192];           // 32 KB: 1024 rec x 8 words (r17)
  __shared__ uint4 znyS[4][64];            // 4 KB: [wave][slot] w0,w1,w2,row
  __shared__ unsigned cnt[8];
  const int b = blockIdx.x & 127, qb = blockIdx.x >> 7;  // qb 0..3
  const int tid = (int)threadIdx.x;
  const int wv = tid >> 6, lane = tid & 63;
  const int c15 = lane & 15, quad = lane >> 4;
  const int n0 = qb * 256;
  const int t = ts[b];
  const float aa = sacp[t], ssv = s1m[t];
  if (tid < ITERS) cnt[tid] = 0u;
  // ---- stage full panel: 4 rows/thread, swizzled pair stores (r17) ---------
#pragma unroll 1
  for (int ii = 0; ii < 4; ++ii) {
    int c = ii * 256 + tid;
    const float2* dp2 = (const float2*)(data + ((size_t)(b << 10) + c) * 6);
    float2 v0 = dp2[0], v1 = dp2[1], v2 = dp2[2];
    float dd[6] = {v0.x, v0.y, v1.x, v1.y, v2.x, v2.y};
    float dsq = dd[0]*dd[0];
    dsq = fmaf(dd[1], dd[1], dsq); dsq = fmaf(dd[2], dd[2], dsq);
    dsq = fmaf(dd[3], dd[3], dsq); dsq = fmaf(dd[4], dd[4], dsq);
    dsq = fmaf(dd[5], dd[5], dsq);
    unsigned U[6];
#pragma unroll
    for (int d = 0; d < 6; ++d) {
      unsigned short hi, lo; split16(dd[d], hi, lo);
      U[d] = pack2(hi, lo);
    }
    unsigned short vh, vl; split16(-0.5f * dsq, vh, vl);
    int sc_ = (c >> 2) & 3;
    unsigned* rec = stw + c * 8;
    *(uint2*)(rec + 2 * (0 ^ sc_)) = make_uint2(U[0], U[1]);
    *(uint2*)(rec + 2 * (1 ^ sc_)) = make_uint2(U[2], U[3]);
    *(uint2*)(rec + 2 * (2 ^ sc_)) = make_uint2(U[4], U[5]);
    *(uint2*)(rec + 2 * (3 ^ sc_)) = make_uint2(pack2(vh, vl), 0u);
  }
  // candidate A-gather base: rows cc*16+c15 -> (row>>2)&3 == c15>>2
  const int abase = c15 * 8 + 2 * (quad ^ (c15 >> 2));
  __syncthreads();
  // ---- per-lane persistent state -------------------------------------------
  const int qrow = n0 + wv * 64 + lane;    // row within batch panel (0..1023)
  const int pg = (b << 10) + qrow;         // global point index
  const float* dpq = data + (size_t)pg * 6;
  const float d3 = dpq[3], d4 = dpq[4], d5 = dpq[5];
  int mpv = 8;
  int myslot = 0;
  // ---- wave-autonomous sequential states -----------------------------------
#pragma unroll 1
  for (int s = 0; s < ITERS; ++s) {
    bool unm = (mpv == 8);
    unsigned long long mask = __ballot(unm ? 1 : 0);
    if (mask == 0ull) break;               // wave done; SIMD freed
    int nUnm = (int)__popcll(mask);
    int nbq = (nUnm + 15) >> 4;            // 1..4 query tiles
    if (unm) {
      float z3, z4, z5;
      if (s == 0) {
        const float* np0 = noise0 + (size_t)pg * 6;
        z3 = np0[3]; z4 = np0[4]; z5 = np0[5];
      } else {
        unsigned kk0 = keys[2*(s-1)], kk1 = keys[2*(s-1)+1];
        unsigned base6 = (unsigned)pg * 6u;
        z3 = nrm_from_idx(kk0, kk1, base6 + 3u);
        z4 = nrm_from_idx(kk0, kk1, base6 + 4u);
        z5 = nrm_from_idx(kk0, kk1, base6 + 5u);
      }
      float v3 = __fadd_rn(__fmul_rn(aa, d3), __fmul_rn(ssv, z3));
      float v4 = __fadd_rn(__fmul_rn(aa, d4), __fmul_rn(ssv, z4));
      float v5 = __fadd_rn(__fmul_rn(aa, d5), __fmul_rn(ssv, z5));
      unsigned short h_, l_;
      unsigned w0, w1, w2;
      split16(v3, h_, l_); w0 = pack2(h_, l_);
      split16(v4, h_, l_); w1 = pack2(h_, l_);
      split16(v5, h_, l_); w2 = pack2(h_, l_);
      int slot = (int)__builtin_amdgcn_mbcnt_hi(
                   (unsigned)(mask >> 32),
                   __builtin_amdgcn_mbcnt_lo((unsigned)mask, 0u));
      myslot = slot;
      znyS[wv][slot] = make_uint4(w0, w1, w2, (unsigned)qrow);
    }
    // build bq[k] + dvv[k] for k < nbq from compacted slots
    half8 bq[4];
    float dvv[4];
#pragma unroll
    for (int k = 0; k < 4; ++k) {
      if (k < nbq) {
        int slot = k * 16 + c15;
        if (slot >= nUnm) slot = 0;        // pad: duplicate slot 0 (unread)
        uint4 zv = znyS[wv][slot];
        int row = (int)zv.w;
        int sw = (row >> 2) & 3;
        uint4 wds = make_uint4(0u, 0u, 0u, 0u);
        if (quad == 0) {
          uint2 u = *(const uint2*)(stw + row * 8 + 2 * (0 ^ sw));
          wds.x = dup_lo(u.x); wds.y = dup_hi(u.x);
          wds.z = dup_lo(u.y); wds.w = dup_hi(u.y);
        } else if (quad == 1) {
          unsigned ud = stw[row * 8 + 2 * (1 ^ sw)];   // dim 2
          wds.x = dup_lo(ud); wds.y = dup_hi(ud);
          wds.z = dup_lo(zv.x); wds.w = dup_hi(zv.x);
        } else if (quad == 2) {
          wds.x = dup_lo(zv.y); wds.y = dup_hi(zv.y);
          wds.z = dup_lo(zv.z); wds.w = dup_hi(zv.z);
        } else {
          wds.x = 0x3C003C00u;
        }
        bq[k] = __builtin_bit_cast(half8, wds);
        // diag: gathered-A row pair 'quad' of this slot's row
        uint2 u2 = *(const uint2*)(stw + row * 8 + 2 * (quad ^ sw));
        half8 ag = __builtin_bit_cast(half8, make_uint4(u2.x, u2.x, u2.y, u2.y));
        f32x4 z = {0.f, 0.f, 0.f, 0.f};
        f32x4 dacc = __builtin_amdgcn_mfma_f32_16x16x32_f16(ag, bq[k], z, 0, 0, 0);
        float d01 = (c15 & 1) ? dacc[1] : dacc[0];
        float d23 = (c15 & 1) ? dacc[3] : dacc[2];
        float dsend = (c15 & 2) ? d23 : d01;
        dvv[k] = __shfl(dsend, ((c15 >> 2) << 4) + c15);
      }
    }
    // sweep all 64 candidate tiles at width nbq
    float bv[4];
    switch (nbq) {
      case 1: sweep64<1>(stw, abase, bq, bv); break;
      case 2: sweep64<2>(stw, abase, bq, bv); break;
      case 3: sweep64<3>(stw, abase, bq, bv); break;
      default: sweep64<4>(stw, abase, bq, bv); break;
    }
    // combine quads, compare vs diag -> wave-uniform 16-bit masks
    unsigned m16_0 = 0u, m16_1 = 0u, m16_2 = 0u, m16_3 = 0u;
#pragma unroll
    for (int k = 0; k < 4; ++k) {
      if (k < nbq) {
        float v = bv[k];
        v = fmaxf(v, __shfl_xor(v, 16));
        v = fmaxf(v, __shfl_xor(v, 32));
        unsigned long long mb = __ballot(v > dvv[k]);
        unsigned mm = (unsigned)(mb & 0xffffu);
        if (k == 0) m16_0 = mm;
        else if (k == 1) m16_1 = mm;
        else if (k == 2) m16_2 = mm;
        else m16_3 = mm;
      }
    }
    // owner-lane mp update via select tree (no dynamic indexing)
    if (unm) {
      int jt = myslot >> 4, jp = myslot & 15;
      unsigned mm = (jt == 0) ? m16_0 : (jt == 1) ? m16_1
                  : (jt == 2) ? m16_2 : m16_3;
      if (((mm >> jp) & 1u) == 0u) mpv = s;
    }
  }
  // ---- epilogue: maskg + block cnt -----------------------------------------
  maskg[pg] = (unsigned char)((1u << mpv) - 1u);
#pragma unroll
  for (int k = 0; k < ITERS; ++k) {
    unsigned long long mk = __ballot(mpv > k ? 1 : 0);
    if (lane == 0) atomicAdd(&cnt[k], (unsigned)__popcll(mk));
  }
  __syncthreads();
  if (tid < ITERS) cntg[tid * 512 + (int)blockIdx.x] = cnt[tid];
}

// ---- kernel 3: MLP + masked SE, with fused finalize (exact cont gate) ------
__global__ __launch_bounds__(256) void k_loss(
    const float* __restrict__ data, const float* __restrict__ noise0,
    const int* __restrict__ ts, const float* __restrict__ sacp,
    const float* __restrict__ s1m, const unsigned* __restrict__ keys,
    const unsigned* __restrict__ cntg, const unsigned char* __restrict__ maskg,
    const float* __restrict__ biasb,
    const float4* __restrict__ PA, const float4* __restrict__ PB,
    const float* __restrict__ PC, const float* __restrict__ b2,
    float* __restrict__ part) {
  __shared__ float4 sA[HID];
  __shared__ float4 sB[HID];
  __shared__ float2 sCb[HID];
  __shared__ float zn[256][6];     // z3..z5, noisy3..5 per local point
  __shared__ float pp[4][3][256];  // per-wave partials
  __shared__ float red[4];
  __shared__ int ksh;
  int b = blockIdx.x >> 2, qq = blockIdx.x & 3;
  int tid = (int)threadIdx.x;
  int wv = tid >> 6, lane = tid & 63;
  // ---- phase 1: kstar from cntg --------------------------------------------
  if (tid < 64) {
    int ks = ITERS;
    for (int k2 = 0; k2 < ITERS; ++k2) {
      unsigned v = 0u;
#pragma unroll
      for (int i = 0; i < 8; ++i) v += cntg[k2 * 512 + i * 64 + tid];
#pragma unroll
      for (int m = 32; m >= 1; m >>= 1) v += (unsigned)__shfl_xor((int)v, m);
      if (v < 10u && ks == ITERS) ks = k2;  // first failing iteration
    }
    if (tid == 0) ksh = ks;
  }
  // stage weights meanwhile
  for (int j = tid; j < HID; j += 256) {
    sA[j] = PA[j]; sB[j] = PB[j];
    sCb[j] = make_float2(PC[j], biasb[(size_t)b * HID + j]);
  }
  __syncthreads();
  // ---- phase 2: finalize this block's 256 points (1 per thread) ------------
  int p0 = (b << 10) + qq * 256;
  {
    int kstar = ksh;
    unsigned gate = (kstar >= ITERS) ? 0xFFu : ((1u << kstar) - 1u);
    int p = p0 + tid;
    int t = ts[b];
    float aa = sacp[t], ssv = s1m[t];
    unsigned m = (unsigned)maskg[p] & gate;
    float z3, z4, z5;
    if (m) {
      int j = 31 - __clz((int)m);  // last applied renoise iteration
      unsigned base6 = (unsigned)p * 6u;
      unsigned kk0 = keys[2*j], kk1 = keys[2*j+1];
      z3 = nrm_from_idx(kk0, kk1, base6 + 3u);
      z4 = nrm_from_idx(kk0, kk1, base6 + 4u);
      z5 = nrm_from_idx(kk0, kk1, base6 + 5u);
    } else {
      const float* np0 = noise0 + (size_t)p * 6;
      z3 = np0[3]; z4 = np0[4]; z5 = np0[5];
    }
    const float* dp = data + (size_t)p * 6;
    zn[tid][0] = z3; zn[tid][1] = z4; zn[tid][2] = z5;
    zn[tid][3] = __fadd_rn(__fmul_rn(aa, dp[3]), __fmul_rn(ssv, z3));
    zn[tid][4] = __fadd_rn(__fmul_rn(aa, dp[4]), __fmul_rn(ssv, z4));
    zn[tid][5] = __fadd_rn(__fmul_rn(aa, dp[5]), __fmul_rn(ssv, z5));
  }
  __syncthreads();
  // ---- phase 3: MLP, j-loop split across the 4 waves -----------------------
  float x[4][6];
  float a0[4], a1[4], a2[4];
#pragma unroll
  for (int q = 0; q < 4; ++q) {
    int pl = q * 64 + lane;
    int p = p0 + pl;
    x[q][0] = data[p*6+0]; x[q][1] = data[p*6+1]; x[q][2] = data[p*6+2];
    x[q][3] = zn[pl][3]; x[q][4] = zn[pl][4]; x[q][5] = zn[pl][5];
    a0[q] = 0.f; a1[q] = 0.f; a2[q] = 0.f;
  }
  int j0 = wv * 128;
#pragma unroll 2
  for (int jj = 0; jj < 128; ++jj) {
    int j = j0 + jj;
    float4 A = sA[j];
    float4 Bv = sB[j];
    float2 Cb = sCb[j];
#pragma unroll
    for (int q = 0; q < 4; ++q) {
      float s = x[q][0] * A.x;
      s = fmaf(x[q][1], A.y, s); s = fmaf(x[q][2], A.z, s);
      s = fmaf(x[q][3], A.w, s); s = fmaf(x[q][4], Bv.x, s);
      s = fmaf(x[q][5], Bv.y, s);
      s += Cb.y;
      float h = ftanh(s);
      a0[q] = fmaf(h, Bv.z, a0[q]);
      a1[q] = fmaf(h, Bv.w, a1[q]);
      a2[q] = fmaf(h, Cb.x, a2[q]);
    }
  }
#pragma unroll
  for (int q = 0; q < 4; ++q) {
    pp[wv][0][q * 64 + lane] = a0[q];
    pp[wv][1][q * 64 + lane] = a1[q];
    pp[wv][2][q * 64 + lane] = a2[q];
  }
  __syncthreads();
  float f0 = (pp[0][0][tid] + pp[1][0][tid] + pp[2][0][tid] + pp[3][0][tid])
             + b2[3] - zn[tid][0];
  float f1 = (pp[0][1][tid] + pp[1][1][tid] + pp[2][1][tid] + pp[3][1][tid])
             + b2[4] - zn[tid][1];
  float f2 = (pp[0][2][tid] + pp[1][2][tid] + pp[2][2][tid] + pp[3][2][tid])
             + b2[5] - zn[tid][2];
  float lsum = f0 * f0;
  lsum = fmaf(f1, f1, lsum);
  lsum = fmaf(f2, f2, lsum);
#pragma unroll
  for (int off = 32; off > 0; off >>= 1) lsum += __shfl_down(lsum, off);
  if ((tid & 63) == 0) red[tid >> 6] = lsum;
  __syncthreads();
  if (tid == 0) part[blockIdx.x] = red[0] + red[1] + red[2] + red[3];
}

// ---- kernel 4: final reduce ------------------------------------------------
__global__ void k_red(const float* __restrict__ part, float* __restrict__ out) {
  int b = (int)threadIdx.x;
  if (b < BS) {
    out[b] = (part[4*b] + part[4*b+1] + part[4*b+2] + part[4*b+3]) / 3072.0f;
  }
}

// ---------------------------------------------------------------------------
extern "C" void kernel_launch(void* const* d_in, const int* in_sizes, int n_in,
                              void* d_out, int out_size, void* d_ws, size_t ws_size,
                              hipStream_t stream) {
  (void)in_sizes; (void)n_in; (void)out_size; (void)ws_size;
  const float* data    = (const float*)d_in[0];
  const float* context = (const float*)d_in[1];
  const float* noise0  = (const float*)d_in[2];
  const float* W1      = (const float*)d_in[3];
  const float* Wc      = (const float*)d_in[4];
  const float* Wt      = (const float*)d_in[5];
  const float* b1      = (const float*)d_in[6];
  const float* W2      = (const float*)d_in[7];
  const float* b2      = (const float*)d_in[8];
  const int*   ts      = (const int*)d_in[9];
  float* out = (float*)d_out;

  char* w = (char*)d_ws;
  float*    sacp   = (float*)(w + OFF_SACP);
  float*    s1m    = (float*)(w + OFF_S1M);
  unsigned* keys   = (unsigned*)(w + OFF_KEYS);
  unsigned* cntg   = (unsigned*)(w + OFF_CNTG);
  unsigned char* maskg = (unsigned char*)(w + OFF_MASK);
  float*    biasb  = (float*)(w + OFF_BIAS);
  float4*   PA     = (float4*)(w + OFF_PA);
  float4*   PB     = (float4*)(w + OFF_PB);
  float*    PC     = (float*)(w + OFF_PC);
  float*    part   = (float*)(w + OFF_PART);

  k_setup<<<258, 256, 0, stream>>>(context, Wc, Wt, b1, ts, biasb,
                                   W1, W2, PA, PB, PC, sacp, s1m, keys);
  k_renoise<<<512, 256, 0, stream>>>(data, noise0, ts, sacp, s1m, keys,
                                     cntg, maskg);
  k_loss<<<512, 256, 0, stream>>>(data, noise0, ts, sacp, s1m, keys, cntg,
                                  maskg, biasb, PA, PB, PC, b2, part);
  k_red<<<1, 128, 0, stream>>>(part, out);
}

// Round 9
// 174.922 us; speedup vs baseline: 1.2043x; 1.0372x over previous
//
#include <hip/hip_runtime.h>
#include <hip/hip_bf16.h>
#include <hip/hip_fp16.h>
#include <math.h>

// ---------------------------------------------------------------------------
// Diffusion renoise-loop + conditional MLP loss, MI355X (gfx950).
// RNG: threefry_partitionable (bit-exact, absmax 0.0 rounds 1-13, 15-17, 19, 20).
// Round 21: four rounds (r13/r15/r17/r20) pin wall time at ~76us across issue
// sums 56-99% and occupancies 14-30%. Invariant: 1024 serial ctc-steps/CU of
// LDS-load->MFMA->fmax chain (~180cyc latency each, 2 waves/SIMD can't hide).
// This round halves the steps: states processed in PAIRS {2j,2j+1} -- one
// sweep evaluates both states' mismatch for points unmatched entering the
// pass (s1 result discarded for s0-matchers = reference freezing). 4 passes
// x 16 ctc = 512 steps/CU, each with 2*nbq independent MFMA chains (2x ILP).
// All verified components (staging, compaction, gather, epilogue) unchanged.
#define BS   128
#define NS   1024
#define HID  512
#define CTX  128
#define TT   100
#define ITERS 8

// ---- workspace layout (bytes) ---------------------------------------------
constexpr size_t OFF_SACP  = 0;         // 100 f32
constexpr size_t OFF_S1M   = 512;       // 100 f32
constexpr size_t OFF_KEYS  = 1024;      // 16 u32
constexpr size_t OFF_CNTG  = 1152;      // u32[8][512] -> 17536
constexpr size_t OFF_MASK  = 33920;     // u8[131072] -> 164992
constexpr size_t OFF_BIAS  = 262144;    // f32[128*512] -> 524288
constexpr size_t OFF_PA    = 524288;    // float4[512] -> 532480
constexpr size_t OFF_PB    = 532480;    // float4[512] -> 540672
constexpr size_t OFF_PC    = 540672;    // f32[512]   -> 542720
constexpr size_t OFF_PART  = 542720;    // f32[512]   -> 544768 (~0.55 MB)

typedef __attribute__((ext_vector_type(8))) _Float16 half8;
typedef __attribute__((ext_vector_type(4))) float f32x4;

// ---- threefry2x32-20 -------------------------------------------------------
__device__ __forceinline__ unsigned rotl32(unsigned x, int r) {
  return (x << r) | (x >> (32 - r));
}
__device__ __forceinline__ void tf2x32(unsigned k0, unsigned k1,
                                       unsigned x0, unsigned x1,
                                       unsigned& o0, unsigned& o1) {
  unsigned k2 = k0 ^ k1 ^ 0x1BD11BDAu;
  x0 += k0; x1 += k1;
#define TF_R4(a,b,c,d) \
  x0 += x1; x1 = rotl32(x1,(a)); x1 ^= x0; \
  x0 += x1; x1 = rotl32(x1,(b)); x1 ^= x0; \
  x0 += x1; x1 = rotl32(x1,(c)); x1 ^= x0; \
  x0 += x1; x1 = rotl32(x1,(d)); x1 ^= x0;
  TF_R4(13,15,26,6)   x0 += k1; x1 += k2 + 1u;
  TF_R4(17,29,16,24)  x0 += k2; x1 += k0 + 2u;
  TF_R4(13,15,26,6)   x0 += k0; x1 += k1 + 3u;
  TF_R4(17,29,16,24)  x0 += k1; x1 += k2 + 4u;
  TF_R4(13,15,26,6)   x0 += k2; x1 += k0 + 5u;
#undef TF_R4
  o0 = x0; o1 = x1;
}

__device__ __forceinline__ float bits_to_u(unsigned bits) {
  float f = __uint_as_float((bits >> 9) | 0x3f800000u) - 1.0f;
  float u = f * 2.0f + (-0.99999994f);
  return fmaxf(-0.99999994f, u);
}

__device__ __forceinline__ float nrm_from_idx(unsigned k0, unsigned k1, unsigned idx) {
  unsigned o0, o1;
  tf2x32(k0, k1, 0u, idx, o0, o1);
  return 1.41421356f * erfinvf(bits_to_u(o0 ^ o1));
}

__device__ __forceinline__ float ftanh(float x) {
  float e = __expf(2.0f * x);
  float r = __builtin_amdgcn_rcpf(e + 1.0f);
  return fmaf(-2.0f, r, 1.0f);
}

// fp16 hi/lo split: x ~= hi + lo with |err| <~ 2^-23 |x|
__device__ __forceinline__ void split16(float x, unsigned short& hi, unsigned short& lo) {
  __half h = __float2half(x);
  float hf = __half2float(h);
  __half l = __float2half(x - hf);
  hi = __half_as_ushort(h);
  lo = __half_as_ushort(l);
}
__device__ __forceinline__ unsigned pack2(unsigned short a, unsigned short b) {
  return (unsigned)a | ((unsigned)b << 16);
}
// duplicate low/high 16-bit half of u into both halves (1 v_perm_b32 each)
__device__ __forceinline__ unsigned dup_lo(unsigned u) {
  return __builtin_amdgcn_perm(u, u, 0x01000100u);  // bytes [0,1,0,1]
}
__device__ __forceinline__ unsigned dup_hi(unsigned u) {
  return __builtin_amdgcn_perm(u, u, 0x03020302u);  // bytes [2,3,2,3]
}

// ---- paired-state candidate sweep: NBQ tiles x 2 states over 64 cand tiles -
template<int NBQ>
__device__ __forceinline__ void sweepP(const unsigned* stw, int abase,
                                       const half8* bq0, const half8* bq1,
                                       float* bv0, float* bv1) {
#pragma unroll
  for (int k = 0; k < NBQ; ++k) {
    bv0[k] = -__builtin_inff();
    bv1[k] = -__builtin_inff();
  }
  uint2 cu[4], cun[4];
#pragma unroll
  for (int cc = 0; cc < 4; ++cc)
    cu[cc] = *(const uint2*)(stw + cc * 128 + abase);
#pragma unroll 1
  for (int ctc = 0; ctc < 16; ++ctc) {
    if (ctc < 15) {
#pragma unroll
      for (int cc = 0; cc < 4; ++cc)
        cun[cc] = *(const uint2*)(stw + ((ctc + 1) * 4 + cc) * 128 + abase);
    }
#pragma unroll
    for (int cc = 0; cc < 4; ++cc) {
      half8 ac = __builtin_bit_cast(half8,
                   make_uint4(cu[cc].x, cu[cc].x, cu[cc].y, cu[cc].y));
      f32x4 z = {0.f, 0.f, 0.f, 0.f};
#pragma unroll
      for (int k = 0; k < NBQ; ++k) {
        f32x4 a = __builtin_amdgcn_mfma_f32_16x16x32_f16(ac, bq0[k], z, 0, 0, 0);
        f32x4 a2 = __builtin_amdgcn_mfma_f32_16x16x32_f16(ac, bq1[k], z, 0, 0, 0);
        bv0[k] = fmaxf(fmaxf(bv0[k], fmaxf(fmaxf(a[0], a[1]), a[2])), a[3]);
        bv1[k] = fmaxf(fmaxf(bv1[k], fmaxf(fmaxf(a2[0], a2[1]), a2[2])), a2[3]);
      }
    }
    if (ctc < 15) {
#pragma unroll
      for (int cc = 0; cc < 4; ++cc) cu[cc] = cun[cc];
    }
  }
}

// ---- kernel 1: setup — blocks 0..255 bias, 256 weight pack, 257 tables -----
__global__ __launch_bounds__(256) void k_setup(
    const float* __restrict__ ctx, const float* __restrict__ Wc,
    const float* __restrict__ Wt, const float* __restrict__ b1,
    const int* __restrict__ ts, float* __restrict__ biasb,
    const float* __restrict__ W1, const float* __restrict__ W2,
    float4* __restrict__ PA, float4* __restrict__ PB, float* __restrict__ PC,
    float* __restrict__ sacp, float* __restrict__ s1m,
    unsigned* __restrict__ keys) {
  if (blockIdx.x == 257) {
    __shared__ double omb[TT];
    int t = threadIdx.x;
    if (t < TT) {
      const double PI = 3.14159265358979323846;
      double t0 = (double)t / TT, t1 = (double)(t + 1) / TT;
      double c0 = cos((t0 + 0.008) / 1.008 * PI * 0.5); double ab0 = c0 * c0;
      double c1 = cos((t1 + 0.008) / 1.008 * PI * 0.5); double ab1 = c1 * c1;
      double beta = 1.0 - ab1 / ab0;
      if (beta > 0.999) beta = 0.999;
      omb[t] = 1.0 - beta;
    }
    __syncthreads();
    if (t < TT) {
      double acp = 1.0;
      for (int i = 0; i <= t; ++i) acp *= omb[i];
      sacp[t] = (float)sqrt(acp);
      s1m[t]  = (float)sqrt(1.0 - acp);
    }
    if (t >= 128 && t < 128 + ITERS) {
      int k = t - 128;
      unsigned o0, o1;
      tf2x32(0u, 42u, 0u, (unsigned)k, o0, o1);
      keys[2*k] = o0; keys[2*k+1] = o1;
    }
    return;
  }
  if (blockIdx.x == 256) {
    for (int j = threadIdx.x; j < HID; j += 256) {
      PA[j] = make_float4(W1[j], W1[512 + j], W1[1024 + j], W1[1536 + j]);
      PB[j] = make_float4(W1[2048 + j], W1[2560 + j], W2[j*6 + 3], W2[j*6 + 4]);
      PC[j] = W2[j*6 + 5];
    }
    return;
  }
  __shared__ float sc[CTX];
  int b = blockIdx.x >> 1;
  int j = (blockIdx.x & 1) * 256 + (int)threadIdx.x;
  if (threadIdx.x < CTX) sc[threadIdx.x] = ctx[(size_t)b * CTX + threadIdx.x];
  __syncthreads();
  float acc = 0.f;
  for (int q = 0; q < CTX; ++q) acc = fmaf(sc[q], Wc[q * HID + j], acc);
  float temb = (float)ts[b] / 100.0f;
  biasb[b * HID + j] = acc + temb * Wt[j] + b1[j];
}

// ---- kernel 2: renoise — 512 blocks (4 q-slices x 128 batches) -------------
// Wave-autonomous paired-state passes with point compaction. Wave owns 64
// queries; per pass j (states 2j,2j+1): ballot+mbcnt compacts unmatched into
// znyS0/znyS1 slots; nbq=ceil(nUnm/16) tiles; sweepP<nbq> evaluates both
// states; mp = s0 if s0-bit clear else s1 if s1-bit clear. No barriers in
// the loop; wave exits when all its points matched.
__global__ __launch_bounds__(256, 2) void k_renoise(
    const float* __restrict__ data, const float* __restrict__ noise0,
    const int* __restrict__ ts, const float* __restrict__ sacp,
    const float* __restrict__ s1m, const unsigned* __restrict__ keys,
    unsigned* __restrict__ cntg, unsigned char* __restrict__ maskg) {
  __shared__ unsigned stw[8192];           // 32 KB: 1024 rec x 8 words (r17)
  __shared__ uint4 znyS0[4][64];           // 4 KB: [wave][slot] s0 words+row
  __shared__ uint4 znyS1[4][64];           // 4 KB: [wave][slot] s1 words
  __shared__ unsigned cnt[8];
  const int b = blockIdx.x & 127, qb = blockIdx.x >> 7;  // qb 0..3
  const int tid = (int)threadIdx.x;
  const int wv = tid >> 6, lane = tid & 63;
  const int c15 = lane & 15, quad = lane >> 4;
  const int n0 = qb * 256;
  const int t = ts[b];
  const float aa = sacp[t], ssv = s1m[t];
  if (tid < ITERS) cnt[tid] = 0u;
  // ---- stage full panel: 4 rows/thread, swizzled pair stores (r17) ---------
#pragma unroll 1
  for (int ii = 0; ii < 4; ++ii) {
    int c = ii * 256 + tid;
    const float2* dp2 = (const float2*)(data + ((size_t)(b << 10) + c) * 6);
    float2 v0 = dp2[0], v1 = dp2[1], v2 = dp2[2];
    float dd[6] = {v0.x, v0.y, v1.x, v1.y, v2.x, v2.y};
    float dsq = dd[0]*dd[0];
    dsq = fmaf(dd[1], dd[1], dsq); dsq = fmaf(dd[2], dd[2], dsq);
    dsq = fmaf(dd[3], dd[3], dsq); dsq = fmaf(dd[4], dd[4], dsq);
    dsq = fmaf(dd[5], dd[5], dsq);
    unsigned U[6];
#pragma unroll
    for (int d = 0; d < 6; ++d) {
      unsigned short hi, lo; split16(dd[d], hi, lo);
      U[d] = pack2(hi, lo);
    }
    unsigned short vh, vl; split16(-0.5f * dsq, vh, vl);
    int sc_ = (c >> 2) & 3;
    unsigned* rec = stw + c * 8;
    *(uint2*)(rec + 2 * (0 ^ sc_)) = make_uint2(U[0], U[1]);
    *(uint2*)(rec + 2 * (1 ^ sc_)) = make_uint2(U[2], U[3]);
    *(uint2*)(rec + 2 * (2 ^ sc_)) = make_uint2(U[4], U[5]);
    *(uint2*)(rec + 2 * (3 ^ sc_)) = make_uint2(pack2(vh, vl), 0u);
  }
  // candidate A-gather base: rows cc*16+c15 -> (row>>2)&3 == c15>>2
  const int abase = c15 * 8 + 2 * (quad ^ (c15 >> 2));
  __syncthreads();
  // ---- per-lane persistent state -------------------------------------------
  const int qrow = n0 + wv * 64 + lane;    // row within batch panel (0..1023)
  const int pg = (b << 10) + qrow;         // global point index
  const float* dpq = data + (size_t)pg * 6;
  const float d3 = dpq[3], d4 = dpq[4], d5 = dpq[5];
  int mpv = 8;
  int myslot = 0;
  // ---- wave-autonomous paired-state passes ---------------------------------
#pragma unroll 1
  for (int j = 0; j < 4; ++j) {
    const int s0 = 2 * j;
    bool unm = (mpv == 8);
    unsigned long long mask = __ballot(unm ? 1 : 0);
    if (mask == 0ull) break;               // wave done; SIMD freed
    int nUnm = (int)__popcll(mask);
    int nbq = (nUnm + 15) >> 4;            // 1..4 query tiles
    if (unm) {
      unsigned base6 = (unsigned)pg * 6u;
      float z3a, z4a, z5a;
      if (j == 0) {
        const float* np0 = noise0 + (size_t)pg * 6;
        z3a = np0[3]; z4a = np0[4]; z5a = np0[5];
      } else {
        unsigned ka0 = keys[2*(s0-1)], ka1 = keys[2*(s0-1)+1];
        z3a = nrm_from_idx(ka0, ka1, base6 + 3u);
        z4a = nrm_from_idx(ka0, ka1, base6 + 4u);
        z5a = nrm_from_idx(ka0, ka1, base6 + 5u);
      }
      unsigned kb0 = keys[2*s0], kb1 = keys[2*s0+1];
      float z3b = nrm_from_idx(kb0, kb1, base6 + 3u);
      float z4b = nrm_from_idx(kb0, kb1, base6 + 4u);
      float z5b = nrm_from_idx(kb0, kb1, base6 + 5u);
      float v3a = __fadd_rn(__fmul_rn(aa, d3), __fmul_rn(ssv, z3a));
      float v4a = __fadd_rn(__fmul_rn(aa, d4), __fmul_rn(ssv, z4a));
      float v5a = __fadd_rn(__fmul_rn(aa, d5), __fmul_rn(ssv, z5a));
      float v3b = __fadd_rn(__fmul_rn(aa, d3), __fmul_rn(ssv, z3b));
      float v4b = __fadd_rn(__fmul_rn(aa, d4), __fmul_rn(ssv, z4b));
      float v5b = __fadd_rn(__fmul_rn(aa, d5), __fmul_rn(ssv, z5b));
      unsigned short h_, l_;
      unsigned w0a, w1a, w2a, w0b, w1b, w2b;
      split16(v3a, h_, l_); w0a = pack2(h_, l_);
      split16(v4a, h_, l_); w1a = pack2(h_, l_);
      split16(v5a, h_, l_); w2a = pack2(h_, l_);
      split16(v3b, h_, l_); w0b = pack2(h_, l_);
      split16(v4b, h_, l_); w1b = pack2(h_, l_);
      split16(v5b, h_, l_); w2b = pack2(h_, l_);
      int slot = (int)__builtin_amdgcn_mbcnt_hi(
                   (unsigned)(mask >> 32),
                   __builtin_amdgcn_mbcnt_lo((unsigned)mask, 0u));
      myslot = slot;
      znyS0[wv][slot] = make_uint4(w0a, w1a, w2a, (unsigned)qrow);
      znyS1[wv][slot] = make_uint4(w0b, w1b, w2b, 0u);
    }
    // build bq0/bq1[k] + dvv0/dvv1[k] for k < nbq from compacted slots
    half8 bq0[4], bq1[4];
    float dvv0[4], dvv1[4];
#pragma unroll
    for (int k = 0; k < 4; ++k) {
      if (k < nbq) {
        int slot = k * 16 + c15;
        if (slot >= nUnm) slot = 0;        // pad: duplicate slot 0 (unread)
        uint4 za = znyS0[wv][slot];
        uint4 zb = znyS1[wv][slot];
        int row = (int)za.w;
        int sw = (row >> 2) & 3;
        uint4 wa = make_uint4(0u, 0u, 0u, 0u);
        uint4 wb = make_uint4(0u, 0u, 0u, 0u);
        if (quad == 0) {
          uint2 u = *(const uint2*)(stw + row * 8 + 2 * (0 ^ sw));
          wa.x = dup_lo(u.x); wa.y = dup_hi(u.x);
          wa.z = dup_lo(u.y); wa.w = dup_hi(u.y);
          wb = wa;
        } else if (quad == 1) {
          unsigned ud = stw[row * 8 + 2 * (1 ^ sw)];   // dim 2
          wa.x = dup_lo(ud); wa.y = dup_hi(ud);
          wa.z = dup_lo(za.x); wa.w = dup_hi(za.x);
          wb.x = wa.x; wb.y = wa.y;
          wb.z = dup_lo(zb.x); wb.w = dup_hi(zb.x);
        } else if (quad == 2) {
          wa.x = dup_lo(za.y); wa.y = dup_hi(za.y);
          wa.z = dup_lo(za.z); wa.w = dup_hi(za.z);
          wb.x = dup_lo(zb.y); wb.y = dup_hi(zb.y);
          wb.z = dup_lo(zb.z); wb.w = dup_hi(zb.z);
        } else {
          wa.x = 0x3C003C00u;
          wb = wa;
        }
        bq0[k] = __builtin_bit_cast(half8, wa);
        bq1[k] = __builtin_bit_cast(half8, wb);
        // diag: gathered-A row pair 'quad' of this slot's row, both states
        uint2 u2 = *(const uint2*)(stw + row * 8 + 2 * (quad ^ sw));
        half8 ag = __builtin_bit_cast(half8, make_uint4(u2.x, u2.x, u2.y, u2.y));
        f32x4 z = {0.f, 0.f, 0.f, 0.f};
        f32x4 da = __builtin_amdgcn_mfma_f32_16x16x32_f16(ag, bq0[k], z, 0, 0, 0);
        f32x4 db = __builtin_amdgcn_mfma_f32_16x16x32_f16(ag, bq1[k], z, 0, 0, 0);
        float d01 = (c15 & 1) ? da[1] : da[0];
        float d23 = (c15 & 1) ? da[3] : da[2];
        float dsend = (c15 & 2) ? d23 : d01;
        dvv0[k] = __shfl(dsend, ((c15 >> 2) << 4) + c15);
        d01 = (c15 & 1) ? db[1] : db[0];
        d23 = (c15 & 1) ? db[3] : db[2];
        dsend = (c15 & 2) ? d23 : d01;
        dvv1[k] = __shfl(dsend, ((c15 >> 2) << 4) + c15);
      }
    }
    // sweep all 64 candidate tiles at width nbq, both states
    float bv0[4], bv1[4];
    switch (nbq) {
      case 1: sweepP<1>(stw, abase, bq0, bq1, bv0, bv1); break;
      case 2: sweepP<2>(stw, abase, bq0, bq1, bv0, bv1); break;
      case 3: sweepP<3>(stw, abase, bq0, bq1, bv0, bv1); break;
      default: sweepP<4>(stw, abase, bq0, bq1, bv0, bv1); break;
    }
    // combine quads, compare vs diag -> wave-uniform 16-bit masks per state
    unsigned m0_0 = 0u, m0_1 = 0u, m0_2 = 0u, m0_3 = 0u;
    unsigned m1_0 = 0u, m1_1 = 0u, m1_2 = 0u, m1_3 = 0u;
#pragma unroll
    for (int k = 0; k < 4; ++k) {
      if (k < nbq) {
        float v = bv0[k];
        v = fmaxf(v, __shfl_xor(v, 16));
        v = fmaxf(v, __shfl_xor(v, 32));
        unsigned mA = (unsigned)(__ballot(v > dvv0[k]) & 0xffffu);
        float w = bv1[k];
        w = fmaxf(w, __shfl_xor(w, 16));
        w = fmaxf(w, __shfl_xor(w, 32));
        unsigned mB = (unsigned)(__ballot(w > dvv1[k]) & 0xffffu);
        if (k == 0) { m0_0 = mA; m1_0 = mB; }
        else if (k == 1) { m0_1 = mA; m1_1 = mB; }
        else if (k == 2) { m0_2 = mA; m1_2 = mB; }
        else { m0_3 = mA; m1_3 = mB; }
      }
    }
    // owner-lane mp update via select tree (no dynamic indexing)
    if (unm) {
      int jt = myslot >> 4, jp = myslot & 15;
      unsigned mA = (jt == 0) ? m0_0 : (jt == 1) ? m0_1
                  : (jt == 2) ? m0_2 : m0_3;
      unsigned mB = (jt == 0) ? m1_0 : (jt == 1) ? m1_1
                  : (jt == 2) ? m1_2 : m1_3;
      if (((mA >> jp) & 1u) == 0u) mpv = s0;
      else if (((mB >> jp) & 1u) == 0u) mpv = s0 + 1;
    }
  }
  // ---- epilogue: maskg + block cnt -----------------------------------------
  maskg[pg] = (unsigned char)((1u << mpv) - 1u);
#pragma unroll
  for (int k = 0; k < ITERS; ++k) {
    unsigned long long mk = __ballot(mpv > k ? 1 : 0);
    if (lane == 0) atomicAdd(&cnt[k], (unsigned)__popcll(mk));
  }
  __syncthreads();
  if (tid < ITERS) cntg[tid * 512 + (int)blockIdx.x] = cnt[tid];
}

// ---- kernel 3: MLP + masked SE, with fused finalize (exact cont gate) ------
__global__ __launch_bounds__(256) void k_loss(
    const float* __restrict__ data, const float* __restrict__ noise0,
    const int* __restrict__ ts, const float* __restrict__ sacp,
    const float* __restrict__ s1m, const unsigned* __restrict__ keys,
    const unsigned* __restrict__ cntg, const unsigned char* __restrict__ maskg,
    const float* __restrict__ biasb,
    const float4* __restrict__ PA, const float4* __restrict__ PB,
    const float* __restrict__ PC, const float* __restrict__ b2,
    float* __restrict__ part) {
  __shared__ float4 sA[HID];
  __shared__ float4 sB[HID];
  __shared__ float2 sCb[HID];
  __shared__ float zn[256][6];     // z3..z5, noisy3..5 per local point
  __shared__ float pp[4][3][256];  // per-wave partials
  __shared__ float red[4];
  __shared__ int ksh;
  int b = blockIdx.x >> 2, qq = blockIdx.x & 3;
  int tid = (int)threadIdx.x;
  int wv = tid >> 6, lane = tid & 63;
  // ---- phase 1: kstar from cntg --------------------------------------------
  if (tid < 64) {
    int ks = ITERS;
    for (int k2 = 0; k2 < ITERS; ++k2) {
      unsigned v = 0u;
#pragma unroll
      for (int i = 0; i < 8; ++i) v += cntg[k2 * 512 + i * 64 + tid];
#pragma unroll
      for (int m = 32; m >= 1; m >>= 1) v += (unsigned)__shfl_xor((int)v, m);
      if (v < 10u && ks == ITERS) ks = k2;  // first failing iteration
    }
    if (tid == 0) ksh = ks;
  }
  // stage weights meanwhile
  for (int j = tid; j < HID; j += 256) {
    sA[j] = PA[j]; sB[j] = PB[j];
    sCb[j] = make_float2(PC[j], biasb[(size_t)b * HID + j]);
  }
  __syncthreads();
  // ---- phase 2: finalize this block's 256 points (1 per thread) ------------
  int p0 = (b << 10) + qq * 256;
  {
    int kstar = ksh;
    unsigned gate = (kstar >= ITERS) ? 0xFFu : ((1u << kstar) - 1u);
    int p = p0 + tid;
    int t = ts[b];
    float aa = sacp[t], ssv = s1m[t];
    unsigned m = (unsigned)maskg[p] & gate;
    float z3, z4, z5;
    if (m) {
      int j = 31 - __clz((int)m);  // last applied renoise iteration
      unsigned base6 = (unsigned)p * 6u;
      unsigned kk0 = keys[2*j], kk1 = keys[2*j+1];
      z3 = nrm_from_idx(kk0, kk1, base6 + 3u);
      z4 = nrm_from_idx(kk0, kk1, base6 + 4u);
      z5 = nrm_from_idx(kk0, kk1, base6 + 5u);
    } else {
      const float* np0 = noise0 + (size_t)p * 6;
      z3 = np0[3]; z4 = np0[4]; z5 = np0[5];
    }
    const float* dp = data + (size_t)p * 6;
    zn[tid][0] = z3; zn[tid][1] = z4; zn[tid][2] = z5;
    zn[tid][3] = __fadd_rn(__fmul_rn(aa, dp[3]), __fmul_rn(ssv, z3));
    zn[tid][4] = __fadd_rn(__fmul_rn(aa, dp[4]), __fmul_rn(ssv, z4));
    zn[tid][5] = __fadd_rn(__fmul_rn(aa, dp[5]), __fmul_rn(ssv, z5));
  }
  __syncthreads();
  // ---- phase 3: MLP, j-loop split across the 4 waves -----------------------
  float x[4][6];
  float a0[4], a1[4], a2[4];
#pragma unroll
  for (int q = 0; q < 4; ++q) {
    int pl = q * 64 + lane;
    int p = p0 + pl;
    x[q][0] = data[p*6+0]; x[q][1] = data[p*6+1]; x[q][2] = data[p*6+2];
    x[q][3] = zn[pl][3]; x[q][4] = zn[pl][4]; x[q][5] = zn[pl][5];
    a0[q] = 0.f; a1[q] = 0.f; a2[q] = 0.f;
  }
  int j0 = wv * 128;
#pragma unroll 2
  for (int jj = 0; jj < 128; ++jj) {
    int j = j0 + jj;
    float4 A = sA[j];
    float4 Bv = sB[j];
    float2 Cb = sCb[j];
#pragma unroll
    for (int q = 0; q < 4; ++q) {
      float s = x[q][0] * A.x;
      s = fmaf(x[q][1], A.y, s); s = fmaf(x[q][2], A.z, s);
      s = fmaf(x[q][3], A.w, s); s = fmaf(x[q][4], Bv.x, s);
      s = fmaf(x[q][5], Bv.y, s);
      s += Cb.y;
      float h = ftanh(s);
      a0[q] = fmaf(h, Bv.z, a0[q]);
      a1[q] = fmaf(h, Bv.w, a1[q]);
      a2[q] = fmaf(h, Cb.x, a2[q]);
    }
  }
#pragma unroll
  for (int q = 0; q < 4; ++q) {
    pp[wv][0][q * 64 + lane] = a0[q];
    pp[wv][1][q * 64 + lane] = a1[q];
    pp[wv][2][q * 64 + lane] = a2[q];
  }
  __syncthreads();
  float f0 = (pp[0][0][tid] + pp[1][0][tid] + pp[2][0][tid] + pp[3][0][tid])
             + b2[3] - zn[tid][0];
  float f1 = (pp[0][1][tid] + pp[1][1][tid] + pp[2][1][tid] + pp[3][1][tid])
             + b2[4] - zn[tid][1];
  float f2 = (pp[0][2][tid] + pp[1][2][tid] + pp[2][2][tid] + pp[3][2][tid])
             + b2[5] - zn[tid][2];
  float lsum = f0 * f0;
  lsum = fmaf(f1, f1, lsum);
  lsum = fmaf(f2, f2, lsum);
#pragma unroll
  for (int off = 32; off > 0; off >>= 1) lsum += __shfl_down(lsum, off);
  if ((tid & 63) == 0) red[tid >> 6] = lsum;
  __syncthreads();
  if (tid == 0) part[blockIdx.x] = red[0] + red[1] + red[2] + red[3];
}

// ---- kernel 4: final reduce ------------------------------------------------
__global__ void k_red(const float* __restrict__ part, float* __restrict__ out) {
  int b = (int)threadIdx.x;
  if (b < BS) {
    out[b] = (part[4*b] + part[4*b+1] + part[4*b+2] + part[4*b+3]) / 3072.0f;
  }
}

// ---------------------------------------------------------------------------
extern "C" void kernel_launch(void* const* d_in, const int* in_sizes, int n_in,
                              void* d_out, int out_size, void* d_ws, size_t ws_size,
                              hipStream_t stream) {
  (void)in_sizes; (void)n_in; (void)out_size; (void)ws_size;
  const float* data    = (const float*)d_in[0];
  const float* context = (const float*)d_in[1];
  const float* noise0  = (const float*)d_in[2];
  const float* W1      = (const float*)d_in[3];
  const float* Wc      = (const float*)d_in[4];
  const float* Wt      = (const float*)d_in[5];
  const float* b1      = (const float*)d_in[6];
  const float* W2      = (const float*)d_in[7];
  const float* b2      = (const float*)d_in[8];
  const int*   ts      = (const int*)d_in[9];
  float* out = (float*)d_out;

  char* w = (char*)d_ws;
  float*    sacp   = (float*)(w + OFF_SACP);
  float*    s1m    = (float*)(w + OFF_S1M);
  unsigned* keys   = (unsigned*)(w + OFF_KEYS);
  unsigned* cntg   = (unsigned*)(w + OFF_CNTG);
  unsigned char* maskg = (unsigned char*)(w + OFF_MASK);
  float*    biasb  = (float*)(w + OFF_BIAS);
  float4*   PA     = (float4*)(w + OFF_PA);
  float4*   PB     = (float4*)(w + OFF_PB);
  float*    PC     = (float*)(w + OFF_PC);
  float*    part   = (float*)(w + OFF_PART);

  k_setup<<<258, 256, 0, stream>>>(context, Wc, Wt, b1, ts, biasb,
                                   W1, W2, PA, PB, PC, sacp, s1m, keys);
  k_renoise<<<512, 256, 0, stream>>>(data, noise0, ts, sacp, s1m, keys,
                                     cntg, maskg);
  k_loss<<<512, 256, 0, stream>>>(data, noise0, ts, sacp, s1m, keys, cntg,
                                  maskg, biasb, PA, PB, PC, b2, part);
  k_red<<<1, 128, 0, stream>>>(part, out);
}